// Round 6
// baseline (723.820 us; speedup 1.0000x reference)
//
#include <hip/hip_runtime.h>
#include <math.h>

#define IN_DIM 16
#define HDIM   128
#define HEADS  4
#define HH     512   // HEADS*HDIM
#define FFH    256   // 2*HDIM
#define NEG_SLOPE 0.2f

typedef _Float16 half8 __attribute__((ext_vector_type(8)));
typedef _Float16 h8 __attribute__((ext_vector_type(8)));
typedef _Float16 h4 __attribute__((ext_vector_type(4)));
typedef _Float16 h2 __attribute__((ext_vector_type(2)));
typedef float f32x4 __attribute__((ext_vector_type(4)));

struct __align__(8) Edge { int src; _Float16 ea0, ea1; };

static __device__ inline float hsum8(h8 v) {
    h4 a = __builtin_shufflevector(v, v, 0, 1, 2, 3) +
           __builtin_shufflevector(v, v, 4, 5, 6, 7);
    h2 b = __builtin_shufflevector(a, a, 0, 1) +
           __builtin_shufflevector(a, a, 2, 3);
    return (float)b[0] + (float)b[1];
}

// ---------------------------------------------------------------------------
// x pad: xh[n][64] = f16(x[n][16]) zero-padded
// ---------------------------------------------------------------------------
__global__ void xpad_kernel(const float* __restrict__ x, _Float16* __restrict__ xh, int n) {
    int idx = blockIdx.x * 256 + threadIdx.x;
    if (idx >= n * 64) return;
    int r = idx >> 6, k = idx & 63;
    xh[idx] = (k < IN_DIM) ? (_Float16)x[r * IN_DIM + k] : (_Float16)0.0f;
}

// ---------------------------------------------------------------------------
// Weight convert+transpose+K-pad: W[Ksrc][N] fp32 -> WT[N][Kd] f16 (zero pad)
// ---------------------------------------------------------------------------
struct WDesc { const float* src; _Float16* dst; int Ksrc; int lgKd; int lgN; };
struct WDescs { WDesc d[15]; };
__global__ void wconv_kernel(WDescs ds) {
    WDesc w = ds.d[blockIdx.y];
    int Kd = 1 << w.lgKd;
    int total = 1 << (w.lgKd + w.lgN);
    for (int idx = blockIdx.x * 256 + threadIdx.x; idx < total; idx += gridDim.x * 256) {
        int n2 = idx >> w.lgKd, k = idx & (Kd - 1);
        w.dst[idx] = (k < w.Ksrc) ? (_Float16)w.src[(k << w.lgN) + n2] : (_Float16)0.0f;
    }
}

// ---------------------------------------------------------------------------
// Preprocess: degree + edge_attr sums (self-loop fill_value='mean')
// ---------------------------------------------------------------------------
__global__ void deg_kernel(const int* __restrict__ ei, const float* __restrict__ eattr,
                           float* deg, float* asum, int E) {
    int e = blockIdx.x * blockDim.x + threadIdx.x;
    if (e >= E) return;
    int d = ei[E + e];
    atomicAdd(&deg[d], 1.0f);
    atomicAdd(&asum[2 * d], eattr[2 * e]);
    atomicAdd(&asum[2 * d + 1], eattr[2 * e + 1]);
}

__global__ void scan_kernel(const float* __restrict__ deg, int* row_ptr, int* cur, int n) {
    __shared__ int sums[1024];
    int tid = threadIdx.x;
    int per = (n + 1023) / 1024;
    int s0 = tid * per;
    int s1 = s0 + per; if (s1 > n) s1 = n;
    int s = 0;
    for (int i = s0; i < s1; i++) s += (int)deg[i] + 1;
    int mysum = s;
    sums[tid] = s;
    __syncthreads();
    // Hillis-Steele inclusive scan over 1024 partials
    for (int dd = 1; dd < 1024; dd <<= 1) {
        int t = (tid >= dd) ? sums[tid - dd] : 0;
        __syncthreads();
        sums[tid] += t;
        __syncthreads();
    }
    int run = sums[tid] - mysum;   // exclusive prefix
    for (int i = s0; i < s1; i++) {
        row_ptr[i] = run; cur[i] = run;
        run += (int)deg[i] + 1;
    }
    if (tid == 1023) row_ptr[n] = sums[1023];
}

__global__ void scatter_kernel(const int* __restrict__ ei, const float* __restrict__ eattr,
                               const float* __restrict__ deg, const float* __restrict__ asum,
                               int* cur, Edge* csr, int E, int n) {
    int i = blockIdx.x * blockDim.x + threadIdx.x;
    if (i >= E + n) return;
    Edge ed;
    int pos;
    if (i < E) {
        int d = ei[E + i];
        pos = atomicAdd(&cur[d], 1);
        ed.src = ei[i];
        ed.ea0 = (_Float16)eattr[2 * i];
        ed.ea1 = (_Float16)eattr[2 * i + 1];
    } else {
        int nd = i - E;
        float dv = fmaxf(deg[nd], 1.0f);
        pos = atomicAdd(&cur[nd], 1);
        ed.src = nd;
        ed.ea0 = (_Float16)(asum[2 * nd] / dv);
        ed.ea1 = (_Float16)(asum[2 * nd + 1] / dv);
    }
    csr[pos] = ed;
}

// ---------------------------------------------------------------------------
// MFMA f16 GEMM: C[M,N] = A[M,K](f16, row-stride lda) @ BT[N][K](f16)
// (+bias)(+GELU). Block tile BMx128, BK=64, 4 waves 2x2, wave (BM/2)x64.
// Requires N%128==0, K%64==0. OUTMODE: 0=f32, 1=f16, 2=both.
// ---------------------------------------------------------------------------
template <int ACT, int OUTMODE, int BM>
__global__ __launch_bounds__(256) void gemm_mfma(const _Float16* __restrict__ A, int lda,
                                                 const _Float16* __restrict__ BT,
                                                 const float* __restrict__ bias,
                                                 float* __restrict__ C32,
                                                 _Float16* __restrict__ C16,
                                                 int M, int N, int K) {
    const int BK = 64, PAD = 8, NI = BM / 32;
    __shared__ _Float16 As[BM][BK + PAD];
    __shared__ _Float16 Bs[128][BK + PAD];
    int tid = threadIdx.x;
    int wave = tid >> 6, lane = tid & 63;
    int quad = lane >> 4, l16 = lane & 15;
    int wrow = (wave >> 1) * (16 * NI);
    int wcol = (wave & 1) * 64;
    int mBase = blockIdx.y * BM;
    int n0 = blockIdx.x * 128;

    f32x4 acc[NI][4] = {};

    for (int k0 = 0; k0 < K; k0 += BK) {
#pragma unroll
        for (int t = 0; t < BM / 32; t++) {
            int idx = tid + t * 256;
            int r = idx >> 3, kb = (idx & 7) * 8;
            half8 hv = {};
            int grow = mBase + r;
            if (grow < M) hv = *(const half8*)(A + (size_t)grow * lda + k0 + kb);
            *(half8*)&As[r][kb] = hv;
        }
#pragma unroll
        for (int t = 0; t < 4; t++) {
            int idx = tid + t * 256;
            int r = idx >> 3, kb = (idx & 7) * 8;
            *(half8*)&Bs[r][kb] = *(const half8*)(BT + (size_t)(n0 + r) * K + k0 + kb);
        }
        __syncthreads();
#pragma unroll
        for (int kc = 0; kc < 2; kc++) {
            half8 a[NI], b[4];
#pragma unroll
            for (int i = 0; i < NI; i++)
                a[i] = *(const half8*)&As[wrow + i * 16 + l16][kc * 32 + quad * 8];
#pragma unroll
            for (int j = 0; j < 4; j++)
                b[j] = *(const half8*)&Bs[wcol + j * 16 + l16][kc * 32 + quad * 8];
#pragma unroll
            for (int i = 0; i < NI; i++)
#pragma unroll
                for (int j = 0; j < 4; j++)
                    acc[i][j] = __builtin_amdgcn_mfma_f32_16x16x32_f16(a[i], b[j], acc[i][j], 0, 0, 0);
        }
        __syncthreads();
    }

#pragma unroll
    for (int i = 0; i < NI; i++) {
#pragma unroll
        for (int r = 0; r < 4; r++) {
            int row = mBase + wrow + i * 16 + quad * 4 + r;
            if (row >= M) continue;
#pragma unroll
            for (int j = 0; j < 4; j++) {
                int col = n0 + wcol + j * 16 + l16;
                float v = acc[i][j][r] + (bias ? bias[col] : 0.0f);
                if (ACT == 1) v = 0.5f * v * (1.0f + erff(v * 0.70710678118654752f));
                if (OUTMODE == 0 || OUTMODE == 2)
                    C32[(size_t)row * N + col] = v;
                if (OUTMODE == 1 || OUTMODE == 2)
                    C16[(size_t)row * N + col] = (_Float16)v;
            }
        }
    }
}

// ---------------------------------------------------------------------------
// Fused GEMM(+bias) + residual + LayerNorm for N=128.
// C = LN(A@BT + bias + R) * g + b, dual write f32 (+f16 if C16).
// BM=64, 4 waves, each wave = 16 rows x 128 cols (8 mfma/k-step).
// ---------------------------------------------------------------------------
__global__ __launch_bounds__(256) void gemm_ln(const _Float16* __restrict__ A, int lda,
                                               const _Float16* __restrict__ BT,
                                               const float* __restrict__ bias,
                                               const float* __restrict__ R,
                                               const float* __restrict__ g,
                                               const float* __restrict__ b,
                                               float* __restrict__ C32,
                                               _Float16* __restrict__ C16,
                                               int M, int K) {
    const int BK = 64, PAD = 8;
    union U {
        struct { _Float16 As[64][BK + PAD]; _Float16 Bs[128][BK + PAD]; } s;
        float lnbuf[64][130];
    };
    __shared__ U u;
    int tid = threadIdx.x;
    int wave = tid >> 6, lane = tid & 63;
    int quad = lane >> 4, l16 = lane & 15;
    int mBase = blockIdx.x * 64;

    f32x4 acc[8] = {};

    for (int k0 = 0; k0 < K; k0 += BK) {
#pragma unroll
        for (int t = 0; t < 2; t++) {
            int idx = tid + t * 256;          // 0..511
            int r = idx >> 3, kb = (idx & 7) * 8;
            half8 hv = {};
            int grow = mBase + r;
            if (grow < M) hv = *(const half8*)(A + (size_t)grow * lda + k0 + kb);
            *(half8*)&u.s.As[r][kb] = hv;
        }
#pragma unroll
        for (int t = 0; t < 4; t++) {
            int idx = tid + t * 256;          // 0..1023
            int r = idx >> 3, kb = (idx & 7) * 8;
            *(half8*)&u.s.Bs[r][kb] = *(const half8*)(BT + (size_t)r * K + k0 + kb);
        }
        __syncthreads();
#pragma unroll
        for (int kc = 0; kc < 2; kc++) {
            half8 a = *(const half8*)&u.s.As[wave * 16 + l16][kc * 32 + quad * 8];
#pragma unroll
            for (int j = 0; j < 8; j++) {
                half8 bb = *(const half8*)&u.s.Bs[j * 16 + l16][kc * 32 + quad * 8];
                acc[j] = __builtin_amdgcn_mfma_f32_16x16x32_f16(a, bb, acc[j], 0, 0, 0);
            }
        }
        __syncthreads();
    }

    // stage acc+bias into LDS (overwrites As/Bs; all compute is done)
#pragma unroll
    for (int j = 0; j < 8; j++) {
        float bj = bias[j * 16 + l16];
#pragma unroll
        for (int r = 0; r < 4; r++)
            u.lnbuf[wave * 16 + quad * 4 + r][j * 16 + l16] = acc[j][r] + bj;
    }
    __syncthreads();

    // LN: each wave handles its 16 rows, full 128 cols across 64 lanes x 2
    int c = lane * 2;
    for (int rr = 0; rr < 16; rr++) {
        int row = mBase + wave * 16 + rr;
        if (row >= M) break;
        size_t base = (size_t)row * HDIM;
        float x0 = u.lnbuf[wave * 16 + rr][c] + R[base + c];
        float x1 = u.lnbuf[wave * 16 + rr][c + 1] + R[base + c + 1];
        float s = x0 + x1;
#pragma unroll
        for (int off2 = 1; off2 < 64; off2 <<= 1) s += __shfl_xor(s, off2);
        float mu = s * (1.0f / HDIM);
        float d0 = x0 - mu, d1 = x1 - mu;
        float vs = d0 * d0 + d1 * d1;
#pragma unroll
        for (int off2 = 1; off2 < 64; off2 <<= 1) vs += __shfl_xor(vs, off2);
        float invstd = rsqrtf(vs * (1.0f / HDIM) + 1e-5f);
        float o0 = d0 * invstd * g[c] + b[c];
        float o1 = d1 * invstd * g[c + 1] + b[c + 1];
        C32[base + c] = o0;
        C32[base + c + 1] = o1;
        if (C16) {
            C16[base + c] = (_Float16)o0;
            C16[base + c + 1] = (_Float16)o1;
        }
    }
}

// ---------------------------------------------------------------------------
// GATv2 attention + aggregation, packed-f16 math, one wave per dst node,
// online softmax, 4-edge unroll (4 gathers in flight). XLR: [n][1024] f16.
// ---------------------------------------------------------------------------
__global__ __launch_bounds__(256) void gat_edge_kernel(
    const _Float16* __restrict__ XLR,
    const int* __restrict__ row_ptr, const Edge* __restrict__ csr,
    const float* __restrict__ We,    // [2,512]
    const float* __restrict__ attW,  // [512]
    const float* __restrict__ cbias, // [512] or [128]
    _Float16* __restrict__ OUT16, float* __restrict__ OUT32, int n, int concat) {
    int tid = threadIdx.x;
    int wave = tid >> 6, lane = tid & 63;
    int node = blockIdx.x * 4 + wave;
    if (node >= n) return;
    int c0 = lane * 8;

    h8 xr8 = *(const h8*)(XLR + (size_t)node * 1024 + 512 + c0);
    h8 w08, w18, att8;
#pragma unroll
    for (int k = 0; k < 8; k++) {
        w08[k] = (_Float16)We[c0 + k];
        w18[k] = (_Float16)We[HH + c0 + k];
        att8[k] = (_Float16)attW[c0 + k];
    }
    const _Float16 slope = (_Float16)NEG_SLOPE;

    h8 acc2 = (h8)(_Float16)0.0f;
    float m = -INFINITY, l = 0.0f;
    int beg = row_ptr[node], end = row_ptr[node + 1];
    int j = beg;
    for (; j + 3 < end; j += 4) {
        Edge e0 = csr[j], e1 = csr[j + 1], e2 = csr[j + 2], e3 = csr[j + 3];
        h8 x0 = *(const h8*)(XLR + (size_t)e0.src * 1024 + c0);
        h8 x1 = *(const h8*)(XLR + (size_t)e1.src * 1024 + c0);
        h8 x2 = *(const h8*)(XLR + (size_t)e2.src * 1024 + c0);
        h8 x3 = *(const h8*)(XLR + (size_t)e3.src * 1024 + c0);
        h8 v0 = x0 + (xr8 + w08 * e0.ea0 + w18 * e0.ea1);
        h8 v1 = x1 + (xr8 + w08 * e1.ea0 + w18 * e1.ea1);
        h8 v2 = x2 + (xr8 + w08 * e2.ea0 + w18 * e2.ea1);
        h8 v3 = x3 + (xr8 + w08 * e3.ea0 + w18 * e3.ea1);
        v0 = __builtin_elementwise_max(v0, v0 * slope);
        v1 = __builtin_elementwise_max(v1, v1 * slope);
        v2 = __builtin_elementwise_max(v2, v2 * slope);
        v3 = __builtin_elementwise_max(v3, v3 * slope);
        float p0 = hsum8(v0 * att8);
        float p1 = hsum8(v1 * att8);
        float p2 = hsum8(v2 * att8);
        float p3 = hsum8(v3 * att8);
#pragma unroll
        for (int off2 = 1; off2 < 16; off2 <<= 1) {
            p0 += __shfl_xor(p0, off2);
            p1 += __shfl_xor(p1, off2);
            p2 += __shfl_xor(p2, off2);
            p3 += __shfl_xor(p3, off2);
        }
        float mnew = fmaxf(fmaxf(m, fmaxf(p0, p1)), fmaxf(p2, p3));
        float sc = __expf(m - mnew);
        float e0f = __expf(p0 - mnew);
        float e1f = __expf(p1 - mnew);
        float e2f = __expf(p2 - mnew);
        float e3f = __expf(p3 - mnew);
        l = l * sc + e0f + e1f + e2f + e3f;
        acc2 = acc2 * (_Float16)sc + x0 * (_Float16)e0f + x1 * (_Float16)e1f
             + x2 * (_Float16)e2f + x3 * (_Float16)e3f;
        m = mnew;
    }
    for (; j < end; j++) {
        Edge e0 = csr[j];
        h8 x0 = *(const h8*)(XLR + (size_t)e0.src * 1024 + c0);
        h8 v0 = x0 + (xr8 + w08 * e0.ea0 + w18 * e0.ea1);
        v0 = __builtin_elementwise_max(v0, v0 * slope);
        float p0 = hsum8(v0 * att8);
#pragma unroll
        for (int off2 = 1; off2 < 16; off2 <<= 1) p0 += __shfl_xor(p0, off2);
        float mnew = fmaxf(m, p0);
        float sc = __expf(m - mnew);
        float e0f = __expf(p0 - mnew);
        l = l * sc + e0f;
        acc2 = acc2 * (_Float16)sc + x0 * (_Float16)e0f;
        m = mnew;
    }
    float invf = 1.0f / (l + 1e-16f);
    if (concat) {
        h8 o = acc2 * (_Float16)invf;
#pragma unroll
        for (int k = 0; k < 8; k++) o[k] = o[k] + (_Float16)cbias[c0 + k];
        *(h8*)(OUT16 + (size_t)node * 1024 + c0) = o;
    } else {
        float o8[8];
#pragma unroll
        for (int k = 0; k < 8; k++) {
            float a = (float)acc2[k] * invf;
            a += __shfl_xor(a, 16);
            a += __shfl_xor(a, 32);
            o8[k] = a;
        }
        if (lane < 16) {
#pragma unroll
            for (int k = 0; k < 8; k++)
                OUT32[(size_t)node * HDIM + c0 + k] = o8[k] * 0.25f + cbias[c0 + k];
        }
    }
}

// ---------------------------------------------------------------------------
// Standalone LayerNorm over (X + R); dual write fp32 (+f16 if OUT16).
// ---------------------------------------------------------------------------
__global__ __launch_bounds__(256) void ln_res_kernel(const float* X, const float* R,
                                                     const float* __restrict__ g,
                                                     const float* __restrict__ b,
                                                     float* OUT32, _Float16* OUT16, int n) {
    int wave = threadIdx.x >> 6, lane = threadIdx.x & 63;
    int row = blockIdx.x * 4 + wave;
    if (row >= n) return;
    int c = lane * 2;
    size_t base = (size_t)row * HDIM;
    float x0 = X[base + c] + R[base + c];
    float x1 = X[base + c + 1] + R[base + c + 1];
    float s = x0 + x1;
#pragma unroll
    for (int off = 1; off < 64; off <<= 1) s += __shfl_xor(s, off);
    float mu = s * (1.0f / HDIM);
    float d0 = x0 - mu, d1 = x1 - mu;
    float vs = d0 * d0 + d1 * d1;
#pragma unroll
    for (int off = 1; off < 64; off <<= 1) vs += __shfl_xor(vs, off);
    float invstd = rsqrtf(vs * (1.0f / HDIM) + 1e-5f);
    float o0 = d0 * invstd * g[c] + b[c];
    float o1 = d1 * invstd * g[c + 1] + b[c + 1];
    OUT32[base + c] = o0;
    OUT32[base + c + 1] = o1;
    if (OUT16) {
        OUT16[base + c] = (_Float16)o0;
        OUT16[base + c + 1] = (_Float16)o1;
    }
}

// ---------------------------------------------------------------------------
extern "C" void kernel_launch(void* const* d_in, const int* in_sizes, int n_in,
                              void* d_out, int out_size, void* d_ws, size_t ws_size,
                              hipStream_t stream) {
    const float* x        = (const float*)d_in[0];
    const int*   ei       = (const int*)d_in[1];
    const float* eattr    = (const float*)d_in[2];
    const float* emb_w    = (const float*)d_in[3];
    const float* emb_b    = (const float*)d_in[4];
    const float* lin_l    = (const float*)d_in[5];
    const float* lin_r    = (const float*)d_in[6];
    const float* lin_edge = (const float*)d_in[7];
    const float* attw     = (const float*)d_in[8];
    const float* cb01     = (const float*)d_in[9];
    const float* cb2      = (const float*)d_in[10];
    const float* proj_w   = (const float*)d_in[11];
    const float* proj_b   = (const float*)d_in[12];
    const float* n1g      = (const float*)d_in[13];
    const float* n1b      = (const float*)d_in[14];
    const float* n2g      = (const float*)d_in[15];
    const float* n2b      = (const float*)d_in[16];
    const float* fw1      = (const float*)d_in[17];
    const float* fb1      = (const float*)d_in[18];
    const float* fw2      = (const float*)d_in[19];
    const float* fb2      = (const float*)d_in[20];
    float* out = (float*)d_out;

    const int n = in_sizes[0] / IN_DIM;   // 20000
    const int E = in_sizes[2] / 2;        // 320000
    const int EP = E + n;

    size_t off = 0;
    auto alloc = [&](size_t bytes) {
        void* p = (char*)d_ws + off;
        off += (bytes + 255) & ~(size_t)255;
        return p;
    };
    float* deg     = (float*)alloc((size_t)n * 4);
    float* asum    = (float*)alloc((size_t)2 * n * 4);
    int*   row_ptr = (int*)alloc((size_t)(n + 1) * 4);
    int*   cur     = (int*)alloc((size_t)n * 4);
    Edge*  csr     = (Edge*)alloc((size_t)EP * 8);
    float* H0      = (float*)alloc((size_t)n * HDIM * 4);
    float* H1      = (float*)alloc((size_t)n * HDIM * 4);
    _Float16* H0h  = (_Float16*)alloc((size_t)n * HDIM * 2);
    _Float16* H1h  = (_Float16*)alloc((size_t)n * HDIM * 2);
    _Float16* MID  = (_Float16*)alloc((size_t)n * FFH * 2);
    _Float16* XLR  = (_Float16*)alloc((size_t)n * 1024 * 2);
    _Float16* xh   = (_Float16*)alloc((size_t)n * 64 * 2);
    _Float16* wt_emb  = (_Float16*)alloc((size_t)HDIM * 64 * 2);
    _Float16* wt_llr  = (_Float16*)alloc((size_t)3 * 1024 * HDIM * 2);
    _Float16* wt_proj = (_Float16*)alloc((size_t)2 * HDIM * HH * 2);
    _Float16* wt_f1   = (_Float16*)alloc((size_t)3 * FFH * HDIM * 2);
    _Float16* wt_f2   = (_Float16*)alloc((size_t)3 * HDIM * FFH * 2);
    (void)ws_size;

    // ---- input prep ----
    xpad_kernel<<<(n * 64 + 255) / 256, 256, 0, stream>>>(x, xh, n);
    WDescs ds;
    int di = 0;
    ds.d[di++] = {emb_w, wt_emb, IN_DIM, 6, 7};
    for (int i = 0; i < 3; i++) {
        ds.d[di++] = {lin_l + (size_t)i * HDIM * HH, wt_llr + (size_t)i * 1024 * HDIM, HDIM, 7, 9};
        ds.d[di++] = {lin_r + (size_t)i * HDIM * HH, wt_llr + (size_t)i * 1024 * HDIM + (size_t)512 * HDIM, HDIM, 7, 9};
    }
    for (int i = 0; i < 2; i++)
        ds.d[di++] = {proj_w + (size_t)i * HH * HDIM, wt_proj + (size_t)i * HDIM * HH, HH, 9, 7};
    for (int i = 0; i < 3; i++)
        ds.d[di++] = {fw1 + (size_t)i * HDIM * FFH, wt_f1 + (size_t)i * FFH * HDIM, HDIM, 7, 8};
    for (int i = 0; i < 3; i++)
        ds.d[di++] = {fw2 + (size_t)i * FFH * HDIM, wt_f2 + (size_t)i * HDIM * FFH, FFH, 8, 7};
    wconv_kernel<<<dim3(32, 15), 256, 0, stream>>>(ds);

    // ---- CSR build ----
    (void)hipMemsetAsync(deg, 0, (size_t)n * 4, stream);
    (void)hipMemsetAsync(asum, 0, (size_t)2 * n * 4, stream);
    deg_kernel<<<(E + 255) / 256, 256, 0, stream>>>(ei, eattr, deg, asum, E);
    scan_kernel<<<1, 1024, 0, stream>>>(deg, row_ptr, cur, n);
    scatter_kernel<<<(EP + 255) / 256, 256, 0, stream>>>(ei, eattr, deg, asum, cur, csr, E, n);

    // ---- Embedding: H0(+H0h) = xh @ wt_emb + emb_b ----
    gemm_mfma<0, 2, 128><<<dim3(1, (n + 127) / 128), 256, 0, stream>>>(
        xh, 64, wt_emb, emb_b, H0, H0h, n, HDIM, 64);

    // ---- 3 GATv2 + FFN layers ----
    for (int i = 0; i < 3; i++) {
        int concat = (i < 2);
        // fused lin_l|lin_r: XLR[n][1024]
        gemm_mfma<0, 1, 128><<<dim3(8, (n + 127) / 128), 256, 0, stream>>>(
            H0h, HDIM, wt_llr + (size_t)i * 1024 * HDIM, nullptr, nullptr, XLR, n, 1024, HDIM);
        gat_edge_kernel<<<(n + 3) / 4, 256, 0, stream>>>(
            XLR, row_ptr, csr,
            lin_edge + (size_t)i * 2 * HH, attw + (size_t)i * HH,
            concat ? (cb01 + (size_t)i * HH) : cb2,
            XLR + 512, H1, n, concat);
        if (concat) {
            // H1 = LN(proj(gatout) + pb + H0), dual write
            gemm_ln<<<(n + 63) / 64, 256, 0, stream>>>(
                XLR + 512, 1024, wt_proj + (size_t)i * HDIM * HH,
                proj_b + (size_t)i * HDIM, H0,
                n1g + (size_t)i * HDIM, n1b + (size_t)i * HDIM,
                H1, H1h, n, HH);
        } else {
            // gat wrote H1 (f32, mean+bias); standalone LN
            ln_res_kernel<<<(n + 3) / 4, 256, 0, stream>>>(
                H1, H0, n1g + (size_t)i * HDIM, n1b + (size_t)i * HDIM, H1, H1h, n);
        }
        gemm_mfma<1, 1, 128><<<dim3(2, (n + 127) / 128), 256, 0, stream>>>(
            H1h, HDIM, wt_f1 + (size_t)i * FFH * HDIM, fb1 + (size_t)i * FFH,
            nullptr, MID, n, FFH, HDIM);
        // out = LN(f2(MID) + b2 + H1), dual write (f32-only on last layer)
        float* lnout = (i == 2) ? out : H0;
        _Float16* lnout16 = (i == 2) ? nullptr : H0h;
        gemm_ln<<<(n + 63) / 64, 256, 0, stream>>>(
            MID, FFH, wt_f2 + (size_t)i * HDIM * FFH, fb2 + (size_t)i * HDIM, H1,
            n2g + (size_t)i * HDIM, n2b + (size_t)i * HDIM,
            lnout, lnout16, n, FFH);
    }
}

// Round 7
// 659.564 us; speedup vs baseline: 1.0974x; 1.0974x over previous
//
#include <hip/hip_runtime.h>
#include <math.h>

#define IN_DIM 16
#define HDIM   128
#define HEADS  4
#define HH     512   // HEADS*HDIM
#define FFH    256   // 2*HDIM
#define NEG_SLOPE 0.2f

typedef _Float16 half8 __attribute__((ext_vector_type(8)));
typedef _Float16 h8 __attribute__((ext_vector_type(8)));
typedef _Float16 h4 __attribute__((ext_vector_type(4)));
typedef _Float16 h2 __attribute__((ext_vector_type(2)));
typedef float f32x4 __attribute__((ext_vector_type(4)));

struct __align__(8) Edge { int src; _Float16 ea0, ea1; };

static __device__ inline float hsum8(h8 v) {
    h4 a = __builtin_shufflevector(v, v, 0, 1, 2, 3) +
           __builtin_shufflevector(v, v, 4, 5, 6, 7);
    h2 b = __builtin_shufflevector(a, a, 0, 1) +
           __builtin_shufflevector(a, a, 2, 3);
    return (float)b[0] + (float)b[1];
}

// ---------------------------------------------------------------------------
// x pad: xh[n][64] = f16(x[n][16]) zero-padded
// ---------------------------------------------------------------------------
__global__ void xpad_kernel(const float* __restrict__ x, _Float16* __restrict__ xh, int n) {
    int idx = blockIdx.x * 256 + threadIdx.x;
    if (idx >= n * 64) return;
    int r = idx >> 6, k = idx & 63;
    xh[idx] = (k < IN_DIM) ? (_Float16)x[r * IN_DIM + k] : (_Float16)0.0f;
}

// ---------------------------------------------------------------------------
// Weight convert+transpose+K-pad: W[Ksrc][N] fp32 -> WT[N][Kd] f16 (zero pad)
// ---------------------------------------------------------------------------
struct WDesc { const float* src; _Float16* dst; int Ksrc; int lgKd; int lgN; };
struct WDescs { WDesc d[15]; };
__global__ void wconv_kernel(WDescs ds) {
    WDesc w = ds.d[blockIdx.y];
    int Kd = 1 << w.lgKd;
    int total = 1 << (w.lgKd + w.lgN);
    for (int idx = blockIdx.x * 256 + threadIdx.x; idx < total; idx += gridDim.x * 256) {
        int n2 = idx >> w.lgKd, k = idx & (Kd - 1);
        w.dst[idx] = (k < w.Ksrc) ? (_Float16)w.src[(k << w.lgN) + n2] : (_Float16)0.0f;
    }
}

// ---------------------------------------------------------------------------
// Preprocess: degree + edge_attr sums (self-loop fill_value='mean')
// ---------------------------------------------------------------------------
__global__ void deg_kernel(const int* __restrict__ ei, const float* __restrict__ eattr,
                           float* deg, float* asum, int E) {
    int e = blockIdx.x * blockDim.x + threadIdx.x;
    if (e >= E) return;
    int d = ei[E + e];
    atomicAdd(&deg[d], 1.0f);
    atomicAdd(&asum[2 * d], eattr[2 * e]);
    atomicAdd(&asum[2 * d + 1], eattr[2 * e + 1]);
}

__global__ void scan_kernel(const float* __restrict__ deg, int* row_ptr, int* cur, int n) {
    __shared__ int sums[1024];
    int tid = threadIdx.x;
    int per = (n + 1023) / 1024;
    int s0 = tid * per;
    int s1 = s0 + per; if (s1 > n) s1 = n;
    int s = 0;
    for (int i = s0; i < s1; i++) s += (int)deg[i] + 1;
    int mysum = s;
    sums[tid] = s;
    __syncthreads();
    for (int dd = 1; dd < 1024; dd <<= 1) {
        int t = (tid >= dd) ? sums[tid - dd] : 0;
        __syncthreads();
        sums[tid] += t;
        __syncthreads();
    }
    int run = sums[tid] - mysum;   // exclusive prefix
    for (int i = s0; i < s1; i++) {
        row_ptr[i] = run; cur[i] = run;
        run += (int)deg[i] + 1;
    }
    if (tid == 1023) row_ptr[n] = sums[1023];
}

__global__ void scatter_kernel(const int* __restrict__ ei, const float* __restrict__ eattr,
                               const float* __restrict__ deg, const float* __restrict__ asum,
                               int* cur, Edge* csr, int E, int n) {
    int i = blockIdx.x * blockDim.x + threadIdx.x;
    if (i >= E + n) return;
    Edge ed;
    int pos;
    if (i < E) {
        int d = ei[E + i];
        pos = atomicAdd(&cur[d], 1);
        ed.src = ei[i];
        ed.ea0 = (_Float16)eattr[2 * i];
        ed.ea1 = (_Float16)eattr[2 * i + 1];
    } else {
        int nd = i - E;
        float dv = fmaxf(deg[nd], 1.0f);
        pos = atomicAdd(&cur[nd], 1);
        ed.src = nd;
        ed.ea0 = (_Float16)(asum[2 * nd] / dv);
        ed.ea1 = (_Float16)(asum[2 * nd + 1] / dv);
    }
    csr[pos] = ed;
}

// ---------------------------------------------------------------------------
// MFMA f16 GEMM: C[M,N] = A[M,K](f16, row-stride lda) @ BT[N][K](f16)
// (+bias)(+GELU). Block tile BMx128, BK=64, 4 waves 2x2, wave (BM/2)x64.
// Requires N%128==0, K%64==0. OUTMODE: 0=f32, 1=f16, 2=both.
// ---------------------------------------------------------------------------
template <int ACT, int OUTMODE, int BM>
__global__ __launch_bounds__(256) void gemm_mfma(const _Float16* __restrict__ A, int lda,
                                                 const _Float16* __restrict__ BT,
                                                 const float* __restrict__ bias,
                                                 float* __restrict__ C32,
                                                 _Float16* __restrict__ C16,
                                                 int M, int N, int K) {
    const int BK = 64, PAD = 8, NI = BM / 32;
    __shared__ _Float16 As[BM][BK + PAD];
    __shared__ _Float16 Bs[128][BK + PAD];
    int tid = threadIdx.x;
    int wave = tid >> 6, lane = tid & 63;
    int quad = lane >> 4, l16 = lane & 15;
    int wrow = (wave >> 1) * (16 * NI);
    int wcol = (wave & 1) * 64;
    int mBase = blockIdx.y * BM;
    int n0 = blockIdx.x * 128;

    f32x4 acc[NI][4] = {};

    for (int k0 = 0; k0 < K; k0 += BK) {
#pragma unroll
        for (int t = 0; t < BM / 32; t++) {
            int idx = tid + t * 256;
            int r = idx >> 3, kb = (idx & 7) * 8;
            half8 hv = {};
            int grow = mBase + r;
            if (grow < M) hv = *(const half8*)(A + (size_t)grow * lda + k0 + kb);
            *(half8*)&As[r][kb] = hv;
        }
#pragma unroll
        for (int t = 0; t < 4; t++) {
            int idx = tid + t * 256;
            int r = idx >> 3, kb = (idx & 7) * 8;
            *(half8*)&Bs[r][kb] = *(const half8*)(BT + (size_t)(n0 + r) * K + k0 + kb);
        }
        __syncthreads();
#pragma unroll
        for (int kc = 0; kc < 2; kc++) {
            half8 a[NI], b[4];
#pragma unroll
            for (int i = 0; i < NI; i++)
                a[i] = *(const half8*)&As[wrow + i * 16 + l16][kc * 32 + quad * 8];
#pragma unroll
            for (int j = 0; j < 4; j++)
                b[j] = *(const half8*)&Bs[wcol + j * 16 + l16][kc * 32 + quad * 8];
#pragma unroll
            for (int i = 0; i < NI; i++)
#pragma unroll
                for (int j = 0; j < 4; j++)
                    acc[i][j] = __builtin_amdgcn_mfma_f32_16x16x32_f16(a[i], b[j], acc[i][j], 0, 0, 0);
        }
        __syncthreads();
    }

#pragma unroll
    for (int i = 0; i < NI; i++) {
#pragma unroll
        for (int r = 0; r < 4; r++) {
            int row = mBase + wrow + i * 16 + quad * 4 + r;
            if (row >= M) continue;
#pragma unroll
            for (int j = 0; j < 4; j++) {
                int col = n0 + wcol + j * 16 + l16;
                float v = acc[i][j][r] + (bias ? bias[col] : 0.0f);
                if (ACT == 1) v = 0.5f * v * (1.0f + erff(v * 0.70710678118654752f));
                if (OUTMODE == 0 || OUTMODE == 2)
                    C32[(size_t)row * N + col] = v;
                if (OUTMODE == 1 || OUTMODE == 2)
                    C16[(size_t)row * N + col] = (_Float16)v;
            }
        }
    }
}

// ---------------------------------------------------------------------------
// Fused GEMM(+bias) + residual + LayerNorm for N=128, register-resident LN.
// C = LN(A@BT + bias + R) * g + b; dual write f32 (+f16 if C16).
// BM=64, 4 waves; wave covers 16 rows x 128 cols. Accumulator layout:
// row = wave*16 + quad*4 + r, col = j*16 + l16. LN stats via 4-level
// shfl_xor butterfly over the l16 group (4 independent rows interleaved).
// ---------------------------------------------------------------------------
__global__ __launch_bounds__(256) void gemm_ln(const _Float16* __restrict__ A, int lda,
                                               const _Float16* __restrict__ BT,
                                               const float* __restrict__ bias,
                                               const float* __restrict__ R,
                                               const float* __restrict__ g,
                                               const float* __restrict__ b,
                                               float* __restrict__ C32,
                                               _Float16* __restrict__ C16,
                                               int M, int K) {
    const int BK = 64, PAD = 8;
    __shared__ _Float16 As[64][BK + PAD];
    __shared__ _Float16 Bs[128][BK + PAD];
    int tid = threadIdx.x;
    int wave = tid >> 6, lane = tid & 63;
    int quad = lane >> 4, l16 = lane & 15;
    int mBase = blockIdx.x * 64;

    f32x4 acc[8] = {};

    for (int k0 = 0; k0 < K; k0 += BK) {
#pragma unroll
        for (int t = 0; t < 2; t++) {
            int idx = tid + t * 256;          // 0..511
            int r = idx >> 3, kb = (idx & 7) * 8;
            half8 hv = {};
            int grow = mBase + r;
            if (grow < M) hv = *(const half8*)(A + (size_t)grow * lda + k0 + kb);
            *(half8*)&As[r][kb] = hv;
        }
#pragma unroll
        for (int t = 0; t < 4; t++) {
            int idx = tid + t * 256;          // 0..1023
            int r = idx >> 3, kb = (idx & 7) * 8;
            *(half8*)&Bs[r][kb] = *(const half8*)(BT + (size_t)r * K + k0 + kb);
        }
        __syncthreads();
#pragma unroll
        for (int kc = 0; kc < 2; kc++) {
            half8 a = *(const half8*)&As[wave * 16 + l16][kc * 32 + quad * 8];
#pragma unroll
            for (int j = 0; j < 8; j++) {
                half8 bb = *(const half8*)&Bs[j * 16 + l16][kc * 32 + quad * 8];
                acc[j] = __builtin_amdgcn_mfma_f32_16x16x32_f16(a, bb, acc[j], 0, 0, 0);
            }
        }
        __syncthreads();
    }

    // ---- epilogue: add bias + residual, register LN, write ----
    float gj[8], bj[8], biasj[8];
#pragma unroll
    for (int j = 0; j < 8; j++) {
        int col = j * 16 + l16;
        biasj[j] = bias[col];
        gj[j] = g[col];
        bj[j] = b[col];
    }
    int row0 = mBase + wave * 16 + quad * 4;
    float sum[4] = {}, sq[4] = {};
#pragma unroll
    for (int r = 0; r < 4; r++) {
        int row = row0 + r;
        bool ok = row < M;
        size_t base = (size_t)row * HDIM;
#pragma unroll
        for (int j = 0; j < 8; j++) {
            float v = acc[j][r] + biasj[j] + (ok ? R[base + j * 16 + l16] : 0.0f);
            acc[j][r] = v;
            sum[r] += v;
            sq[r] += v * v;
        }
    }
#pragma unroll
    for (int r = 0; r < 4; r++) {
#pragma unroll
        for (int off = 1; off < 16; off <<= 1) {
            sum[r] += __shfl_xor(sum[r], off);
            sq[r] += __shfl_xor(sq[r], off);
        }
    }
#pragma unroll
    for (int r = 0; r < 4; r++) {
        int row = row0 + r;
        if (row >= M) continue;
        size_t base = (size_t)row * HDIM;
        float mu = sum[r] * (1.0f / HDIM);
        float var = sq[r] * (1.0f / HDIM) - mu * mu;
        float invstd = rsqrtf(var + 1e-5f);
#pragma unroll
        for (int j = 0; j < 8; j++) {
            float o = (acc[j][r] - mu) * invstd * gj[j] + bj[j];
            C32[base + j * 16 + l16] = o;
            if (C16) C16[base + j * 16 + l16] = (_Float16)o;
        }
    }
}

// ---------------------------------------------------------------------------
// GATv2 attention + aggregation, packed-f16 math, one wave per dst node,
// online softmax, 2-edge unroll. XLR: [n][1024] f16 (XL 0..511, XR 512..1023).
// ---------------------------------------------------------------------------
__global__ __launch_bounds__(256) void gat_edge_kernel(
    const _Float16* __restrict__ XLR,
    const int* __restrict__ row_ptr, const Edge* __restrict__ csr,
    const float* __restrict__ We,    // [2,512]
    const float* __restrict__ attW,  // [512]
    const float* __restrict__ cbias, // [512] or [128]
    _Float16* __restrict__ OUT16, float* __restrict__ OUT32, int n, int concat) {
    int tid = threadIdx.x;
    int wave = tid >> 6, lane = tid & 63;
    int node = blockIdx.x * 4 + wave;
    if (node >= n) return;
    int c0 = lane * 8;

    h8 xr8 = *(const h8*)(XLR + (size_t)node * 1024 + 512 + c0);
    h8 w08, w18, att8;
#pragma unroll
    for (int k = 0; k < 8; k++) {
        w08[k] = (_Float16)We[c0 + k];
        w18[k] = (_Float16)We[HH + c0 + k];
        att8[k] = (_Float16)attW[c0 + k];
    }
    const _Float16 slope = (_Float16)NEG_SLOPE;

    h8 acc2 = (h8)(_Float16)0.0f;
    float m = -INFINITY, l = 0.0f;
    int beg = row_ptr[node], end = row_ptr[node + 1];
    int j = beg;
    for (; j + 1 < end; j += 2) {
        Edge e0 = csr[j], e1 = csr[j + 1];
        h8 x0 = *(const h8*)(XLR + (size_t)e0.src * 1024 + c0);
        h8 x1 = *(const h8*)(XLR + (size_t)e1.src * 1024 + c0);
        h8 v0 = x0 + (xr8 + w08 * e0.ea0 + w18 * e0.ea1);
        h8 v1 = x1 + (xr8 + w08 * e1.ea0 + w18 * e1.ea1);
        v0 = __builtin_elementwise_max(v0, v0 * slope);
        v1 = __builtin_elementwise_max(v1, v1 * slope);
        float p0 = hsum8(v0 * att8);
        float p1 = hsum8(v1 * att8);
        p0 += __shfl_xor(p0, 1); p1 += __shfl_xor(p1, 1);
        p0 += __shfl_xor(p0, 2); p1 += __shfl_xor(p1, 2);
        p0 += __shfl_xor(p0, 4); p1 += __shfl_xor(p1, 4);
        p0 += __shfl_xor(p0, 8); p1 += __shfl_xor(p1, 8);
        float mnew = fmaxf(m, fmaxf(p0, p1));
        float sc = __expf(m - mnew);
        float e0f = __expf(p0 - mnew);
        float e1f = __expf(p1 - mnew);
        l = l * sc + e0f + e1f;
        acc2 = acc2 * (_Float16)sc + x0 * (_Float16)e0f + x1 * (_Float16)e1f;
        m = mnew;
    }
    if (j < end) {
        Edge e0 = csr[j];
        h8 x0 = *(const h8*)(XLR + (size_t)e0.src * 1024 + c0);
        h8 v0 = x0 + (xr8 + w08 * e0.ea0 + w18 * e0.ea1);
        v0 = __builtin_elementwise_max(v0, v0 * slope);
        float p0 = hsum8(v0 * att8);
        p0 += __shfl_xor(p0, 1);
        p0 += __shfl_xor(p0, 2);
        p0 += __shfl_xor(p0, 4);
        p0 += __shfl_xor(p0, 8);
        float mnew = fmaxf(m, p0);
        float sc = __expf(m - mnew);
        float e0f = __expf(p0 - mnew);
        l = l * sc + e0f;
        acc2 = acc2 * (_Float16)sc + x0 * (_Float16)e0f;
        m = mnew;
    }
    float invf = 1.0f / (l + 1e-16f);
    if (concat) {
        h8 o = acc2 * (_Float16)invf;
#pragma unroll
        for (int k = 0; k < 8; k++) o[k] = o[k] + (_Float16)cbias[c0 + k];
        *(h8*)(OUT16 + (size_t)node * 1024 + c0) = o;
    } else {
        float o8[8];
#pragma unroll
        for (int k = 0; k < 8; k++) {
            float a = (float)acc2[k] * invf;
            a += __shfl_xor(a, 16);
            a += __shfl_xor(a, 32);
            o8[k] = a;
        }
        if (lane < 16) {
#pragma unroll
            for (int k = 0; k < 8; k++)
                OUT32[(size_t)node * HDIM + c0 + k] = o8[k] * 0.25f + cbias[c0 + k];
        }
    }
}

// ---------------------------------------------------------------------------
// Standalone LayerNorm over (X + R); dual write fp32 (+f16 if OUT16).
// ---------------------------------------------------------------------------
__global__ __launch_bounds__(256) void ln_res_kernel(const float* X, const float* R,
                                                     const float* __restrict__ g,
                                                     const float* __restrict__ b,
                                                     float* OUT32, _Float16* OUT16, int n) {
    int wave = threadIdx.x >> 6, lane = threadIdx.x & 63;
    int row = blockIdx.x * 4 + wave;
    if (row >= n) return;
    int c = lane * 2;
    size_t base = (size_t)row * HDIM;
    float x0 = X[base + c] + R[base + c];
    float x1 = X[base + c + 1] + R[base + c + 1];
    float s = x0 + x1;
#pragma unroll
    for (int off = 1; off < 64; off <<= 1) s += __shfl_xor(s, off);
    float mu = s * (1.0f / HDIM);
    float d0 = x0 - mu, d1 = x1 - mu;
    float vs = d0 * d0 + d1 * d1;
#pragma unroll
    for (int off = 1; off < 64; off <<= 1) vs += __shfl_xor(vs, off);
    float invstd = rsqrtf(vs * (1.0f / HDIM) + 1e-5f);
    float o0 = d0 * invstd * g[c] + b[c];
    float o1 = d1 * invstd * g[c + 1] + b[c + 1];
    OUT32[base + c] = o0;
    OUT32[base + c + 1] = o1;
    if (OUT16) {
        OUT16[base + c] = (_Float16)o0;
        OUT16[base + c + 1] = (_Float16)o1;
    }
}

// ---------------------------------------------------------------------------
extern "C" void kernel_launch(void* const* d_in, const int* in_sizes, int n_in,
                              void* d_out, int out_size, void* d_ws, size_t ws_size,
                              hipStream_t stream) {
    const float* x        = (const float*)d_in[0];
    const int*   ei       = (const int*)d_in[1];
    const float* eattr    = (const float*)d_in[2];
    const float* emb_w    = (const float*)d_in[3];
    const float* emb_b    = (const float*)d_in[4];
    const float* lin_l    = (const float*)d_in[5];
    const float* lin_r    = (const float*)d_in[6];
    const float* lin_edge = (const float*)d_in[7];
    const float* attw     = (const float*)d_in[8];
    const float* cb01     = (const float*)d_in[9];
    const float* cb2      = (const float*)d_in[10];
    const float* proj_w   = (const float*)d_in[11];
    const float* proj_b   = (const float*)d_in[12];
    const float* n1g      = (const float*)d_in[13];
    const float* n1b      = (const float*)d_in[14];
    const float* n2g      = (const float*)d_in[15];
    const float* n2b      = (const float*)d_in[16];
    const float* fw1      = (const float*)d_in[17];
    const float* fb1      = (const float*)d_in[18];
    const float* fw2      = (const float*)d_in[19];
    const float* fb2      = (const float*)d_in[20];
    float* out = (float*)d_out;

    const int n = in_sizes[0] / IN_DIM;   // 20000
    const int E = in_sizes[2] / 2;        // 320000
    const int EP = E + n;

    size_t off = 0;
    auto alloc = [&](size_t bytes) {
        void* p = (char*)d_ws + off;
        off += (bytes + 255) & ~(size_t)255;
        return p;
    };
    float* deg     = (float*)alloc((size_t)n * 4);
    float* asum    = (float*)alloc((size_t)2 * n * 4);
    int*   row_ptr = (int*)alloc((size_t)(n + 1) * 4);
    int*   cur     = (int*)alloc((size_t)n * 4);
    Edge*  csr     = (Edge*)alloc((size_t)EP * 8);
    float* H0      = (float*)alloc((size_t)n * HDIM * 4);
    float* H1      = (float*)alloc((size_t)n * HDIM * 4);
    _Float16* H0h  = (_Float16*)alloc((size_t)n * HDIM * 2);
    _Float16* H1h  = (_Float16*)alloc((size_t)n * HDIM * 2);
    _Float16* MID  = (_Float16*)alloc((size_t)n * FFH * 2);
    _Float16* XLR  = (_Float16*)alloc((size_t)n * 1024 * 2);
    _Float16* xh   = (_Float16*)alloc((size_t)n * 64 * 2);
    _Float16* wt_emb  = (_Float16*)alloc((size_t)HDIM * 64 * 2);
    _Float16* wt_llr  = (_Float16*)alloc((size_t)3 * 1024 * HDIM * 2);
    _Float16* wt_proj = (_Float16*)alloc((size_t)2 * HDIM * HH * 2);
    _Float16* wt_f1   = (_Float16*)alloc((size_t)3 * FFH * HDIM * 2);
    _Float16* wt_f2   = (_Float16*)alloc((size_t)3 * HDIM * FFH * 2);
    (void)ws_size;

    // ---- input prep ----
    xpad_kernel<<<(n * 64 + 255) / 256, 256, 0, stream>>>(x, xh, n);
    WDescs ds;
    int di = 0;
    ds.d[di++] = {emb_w, wt_emb, IN_DIM, 6, 7};
    for (int i = 0; i < 3; i++) {
        ds.d[di++] = {lin_l + (size_t)i * HDIM * HH, wt_llr + (size_t)i * 1024 * HDIM, HDIM, 7, 9};
        ds.d[di++] = {lin_r + (size_t)i * HDIM * HH, wt_llr + (size_t)i * 1024 * HDIM + (size_t)512 * HDIM, HDIM, 7, 9};
    }
    for (int i = 0; i < 2; i++)
        ds.d[di++] = {proj_w + (size_t)i * HH * HDIM, wt_proj + (size_t)i * HDIM * HH, HH, 9, 7};
    for (int i = 0; i < 3; i++)
        ds.d[di++] = {fw1 + (size_t)i * HDIM * FFH, wt_f1 + (size_t)i * FFH * HDIM, HDIM, 7, 8};
    for (int i = 0; i < 3; i++)
        ds.d[di++] = {fw2 + (size_t)i * FFH * HDIM, wt_f2 + (size_t)i * HDIM * FFH, FFH, 8, 7};
    wconv_kernel<<<dim3(32, 15), 256, 0, stream>>>(ds);

    // ---- CSR build ----
    (void)hipMemsetAsync(deg, 0, (size_t)n * 4, stream);
    (void)hipMemsetAsync(asum, 0, (size_t)2 * n * 4, stream);
    deg_kernel<<<(E + 255) / 256, 256, 0, stream>>>(ei, eattr, deg, asum, E);
    scan_kernel<<<1, 1024, 0, stream>>>(deg, row_ptr, cur, n);
    scatter_kernel<<<(EP + 255) / 256, 256, 0, stream>>>(ei, eattr, deg, asum, cur, csr, E, n);

    // ---- Embedding: H0(+H0h) = xh @ wt_emb + emb_b ----
    gemm_mfma<0, 2, 128><<<dim3(1, (n + 127) / 128), 256, 0, stream>>>(
        xh, 64, wt_emb, emb_b, H0, H0h, n, HDIM, 64);

    // ---- 3 GATv2 + FFN layers ----
    for (int i = 0; i < 3; i++) {
        int concat = (i < 2);
        // fused lin_l|lin_r: XLR[n][1024]
        gemm_mfma<0, 1, 128><<<dim3(8, (n + 127) / 128), 256, 0, stream>>>(
            H0h, HDIM, wt_llr + (size_t)i * 1024 * HDIM, nullptr, nullptr, XLR, n, 1024, HDIM);
        gat_edge_kernel<<<(n + 3) / 4, 256, 0, stream>>>(
            XLR, row_ptr, csr,
            lin_edge + (size_t)i * 2 * HH, attw + (size_t)i * HH,
            concat ? (cb01 + (size_t)i * HH) : cb2,
            XLR + 512, H1, n, concat);
        if (concat) {
            // H1,H1h = LN(proj(gatout) + pb + H0)
            gemm_ln<<<(n + 63) / 64, 256, 0, stream>>>(
                XLR + 512, 1024, wt_proj + (size_t)i * HDIM * HH,
                proj_b + (size_t)i * HDIM, H0,
                n1g + (size_t)i * HDIM, n1b + (size_t)i * HDIM,
                H1, H1h, n, HH);
        } else {
            ln_res_kernel<<<(n + 3) / 4, 256, 0, stream>>>(
                H1, H0, n1g + (size_t)i * HDIM, n1b + (size_t)i * HDIM, H1, H1h, n);
        }
        gemm_mfma<1, 1, 128><<<dim3(2, (n + 127) / 128), 256, 0, stream>>>(
            H1h, HDIM, wt_f1 + (size_t)i * FFH * HDIM, fb1 + (size_t)i * FFH,
            nullptr, MID, n, FFH, HDIM);
        // {out|H0,H0h} = LN(f2(MID) + b2 + H1)
        float* lnout = (i == 2) ? out : H0;
        _Float16* lnout16 = (i == 2) ? nullptr : H0h;
        gemm_ln<<<(n + 63) / 64, 256, 0, stream>>>(
            MID, FFH, wt_f2 + (size_t)i * HDIM * FFH, fb2 + (size_t)i * HDIM, H1,
            n2g + (size_t)i * HDIM, n2b + (size_t)i * HDIM,
            lnout, lnout16, n, FFH);
    }
}

// Round 8
// 600.211 us; speedup vs baseline: 1.2059x; 1.0989x over previous
//
#include <hip/hip_runtime.h>
#include <math.h>

#define IN_DIM 16
#define HDIM   128
#define HEADS  4
#define HH     512   // HEADS*HDIM
#define FFH    256   // 2*HDIM
#define NEG_SLOPE 0.2f

typedef _Float16 half8 __attribute__((ext_vector_type(8)));
typedef _Float16 h8 __attribute__((ext_vector_type(8)));
typedef _Float16 h4 __attribute__((ext_vector_type(4)));
typedef _Float16 h2 __attribute__((ext_vector_type(2)));
typedef float f32x4 __attribute__((ext_vector_type(4)));

struct __align__(8) Edge { int src; _Float16 ea0, ea1; };

static __device__ inline float hsum8(h8 v) {
    h4 a = __builtin_shufflevector(v, v, 0, 1, 2, 3) +
           __builtin_shufflevector(v, v, 4, 5, 6, 7);
    h2 b = __builtin_shufflevector(a, a, 0, 1) +
           __builtin_shufflevector(a, a, 2, 3);
    return (float)b[0] + (float)b[1];
}

// ---------------------------------------------------------------------------
// x pad: xh[n][64] = f16(x[n][16]) zero-padded
// ---------------------------------------------------------------------------
__global__ void xpad_kernel(const float* __restrict__ x, _Float16* __restrict__ xh, int n) {
    int idx = blockIdx.x * 256 + threadIdx.x;
    if (idx >= n * 64) return;
    int r = idx >> 6, k = idx & 63;
    xh[idx] = (k < IN_DIM) ? (_Float16)x[r * IN_DIM + k] : (_Float16)0.0f;
}

// ---------------------------------------------------------------------------
// Weight convert+transpose+K-pad: W[Ksrc][N] fp32 -> WT[N][Kd] f16 (zero pad)
// ---------------------------------------------------------------------------
struct WDesc { const float* src; _Float16* dst; int Ksrc; int lgKd; int lgN; };
struct WDescs { WDesc d[15]; };
__global__ void wconv_kernel(WDescs ds) {
    WDesc w = ds.d[blockIdx.y];
    int Kd = 1 << w.lgKd;
    int total = 1 << (w.lgKd + w.lgN);
    for (int idx = blockIdx.x * 256 + threadIdx.x; idx < total; idx += gridDim.x * 256) {
        int n2 = idx >> w.lgKd, k = idx & (Kd - 1);
        w.dst[idx] = (k < w.Ksrc) ? (_Float16)w.src[(k << w.lgN) + n2] : (_Float16)0.0f;
    }
}

// ---------------------------------------------------------------------------
// Preprocess: degree + edge_attr sums (self-loop fill_value='mean')
// ---------------------------------------------------------------------------
__global__ void deg_kernel(const int* __restrict__ ei, const float* __restrict__ eattr,
                           float* deg, float* asum, int E) {
    int e = blockIdx.x * blockDim.x + threadIdx.x;
    if (e >= E) return;
    int d = ei[E + e];
    atomicAdd(&deg[d], 1.0f);
    atomicAdd(&asum[2 * d], eattr[2 * e]);
    atomicAdd(&asum[2 * d + 1], eattr[2 * e + 1]);
}

__global__ void scan_kernel(const float* __restrict__ deg, int* row_ptr, int* cur, int n) {
    __shared__ int sums[1024];
    int tid = threadIdx.x;
    int per = (n + 1023) / 1024;
    int s0 = tid * per;
    int s1 = s0 + per; if (s1 > n) s1 = n;
    int s = 0;
    for (int i = s0; i < s1; i++) s += (int)deg[i] + 1;
    int mysum = s;
    sums[tid] = s;
    __syncthreads();
    for (int dd = 1; dd < 1024; dd <<= 1) {
        int t = (tid >= dd) ? sums[tid - dd] : 0;
        __syncthreads();
        sums[tid] += t;
        __syncthreads();
    }
    int run = sums[tid] - mysum;   // exclusive prefix
    for (int i = s0; i < s1; i++) {
        row_ptr[i] = run; cur[i] = run;
        run += (int)deg[i] + 1;
    }
    if (tid == 1023) row_ptr[n] = sums[1023];
}

__global__ void scatter_kernel(const int* __restrict__ ei, const float* __restrict__ eattr,
                               const float* __restrict__ deg, const float* __restrict__ asum,
                               int* cur, Edge* csr, int E, int n) {
    int i = blockIdx.x * blockDim.x + threadIdx.x;
    if (i >= E + n) return;
    Edge ed;
    int pos;
    if (i < E) {
        int d = ei[E + i];
        pos = atomicAdd(&cur[d], 1);
        ed.src = ei[i];
        ed.ea0 = (_Float16)eattr[2 * i];
        ed.ea1 = (_Float16)eattr[2 * i + 1];
    } else {
        int nd = i - E;
        float dv = fmaxf(deg[nd], 1.0f);
        pos = atomicAdd(&cur[nd], 1);
        ed.src = nd;
        ed.ea0 = (_Float16)(asum[2 * nd] / dv);
        ed.ea1 = (_Float16)(asum[2 * nd + 1] / dv);
    }
    csr[pos] = ed;
}

// ---------------------------------------------------------------------------
// MFMA f16 GEMM: C[M,N] = A[M,K](f16, row-stride lda) @ BT[N][K](f16)
// (+bias). Block tile BMx128, BK=64, 4 waves 2x2, wave (BM/2)x64.
// Requires N%128==0, K%64==0. OUTMODE: 0=f32, 1=f16, 2=both.
// ---------------------------------------------------------------------------
template <int OUTMODE, int BM>
__global__ __launch_bounds__(256) void gemm_mfma(const _Float16* __restrict__ A, int lda,
                                                 const _Float16* __restrict__ BT,
                                                 const float* __restrict__ bias,
                                                 float* __restrict__ C32,
                                                 _Float16* __restrict__ C16,
                                                 int M, int N, int K) {
    const int BK = 64, PAD = 8, NI = BM / 32;
    __shared__ _Float16 As[BM][BK + PAD];
    __shared__ _Float16 Bs[128][BK + PAD];
    int tid = threadIdx.x;
    int wave = tid >> 6, lane = tid & 63;
    int quad = lane >> 4, l16 = lane & 15;
    int wrow = (wave >> 1) * (16 * NI);
    int wcol = (wave & 1) * 64;
    int mBase = blockIdx.y * BM;
    int n0 = blockIdx.x * 128;

    f32x4 acc[NI][4] = {};

    for (int k0 = 0; k0 < K; k0 += BK) {
#pragma unroll
        for (int t = 0; t < BM / 32; t++) {
            int idx = tid + t * 256;
            int r = idx >> 3, kb = (idx & 7) * 8;
            half8 hv = {};
            int grow = mBase + r;
            if (grow < M) hv = *(const half8*)(A + (size_t)grow * lda + k0 + kb);
            *(half8*)&As[r][kb] = hv;
        }
#pragma unroll
        for (int t = 0; t < 4; t++) {
            int idx = tid + t * 256;
            int r = idx >> 3, kb = (idx & 7) * 8;
            *(half8*)&Bs[r][kb] = *(const half8*)(BT + (size_t)(n0 + r) * K + k0 + kb);
        }
        __syncthreads();
#pragma unroll
        for (int kc = 0; kc < 2; kc++) {
            half8 a[NI], b[4];
#pragma unroll
            for (int i = 0; i < NI; i++)
                a[i] = *(const half8*)&As[wrow + i * 16 + l16][kc * 32 + quad * 8];
#pragma unroll
            for (int j = 0; j < 4; j++)
                b[j] = *(const half8*)&Bs[wcol + j * 16 + l16][kc * 32 + quad * 8];
#pragma unroll
            for (int i = 0; i < NI; i++)
#pragma unroll
                for (int j = 0; j < 4; j++)
                    acc[i][j] = __builtin_amdgcn_mfma_f32_16x16x32_f16(a[i], b[j], acc[i][j], 0, 0, 0);
        }
        __syncthreads();
    }

#pragma unroll
    for (int i = 0; i < NI; i++) {
#pragma unroll
        for (int r = 0; r < 4; r++) {
            int row = mBase + wrow + i * 16 + quad * 4 + r;
            if (row >= M) continue;
#pragma unroll
            for (int j = 0; j < 4; j++) {
                int col = n0 + wcol + j * 16 + l16;
                float v = acc[i][j][r] + (bias ? bias[col] : 0.0f);
                if (OUTMODE == 0 || OUTMODE == 2)
                    C32[(size_t)row * N + col] = v;
                if (OUTMODE == 1 || OUTMODE == 2)
                    C16[(size_t)row * N + col] = (_Float16)v;
            }
        }
    }
}

// ---------------------------------------------------------------------------
// Fused GEMM(+bias) + residual + LayerNorm for N=128, register-resident LN.
// C = LN(A@BT + bias + R) * g + b; dual write f32 (+f16 if C16).
// BM=64, 4 waves; wave covers 16 rows x 128 cols.
// ---------------------------------------------------------------------------
__global__ __launch_bounds__(256) void gemm_ln(const _Float16* __restrict__ A, int lda,
                                               const _Float16* __restrict__ BT,
                                               const float* __restrict__ bias,
                                               const float* __restrict__ R,
                                               const float* __restrict__ g,
                                               const float* __restrict__ b,
                                               float* __restrict__ C32,
                                               _Float16* __restrict__ C16,
                                               int M, int K) {
    const int BK = 64, PAD = 8;
    __shared__ _Float16 As[64][BK + PAD];
    __shared__ _Float16 Bs[128][BK + PAD];
    int tid = threadIdx.x;
    int wave = tid >> 6, lane = tid & 63;
    int quad = lane >> 4, l16 = lane & 15;
    int mBase = blockIdx.x * 64;

    f32x4 acc[8] = {};

    for (int k0 = 0; k0 < K; k0 += BK) {
#pragma unroll
        for (int t = 0; t < 2; t++) {
            int idx = tid + t * 256;          // 0..511
            int r = idx >> 3, kb = (idx & 7) * 8;
            half8 hv = {};
            int grow = mBase + r;
            if (grow < M) hv = *(const half8*)(A + (size_t)grow * lda + k0 + kb);
            *(half8*)&As[r][kb] = hv;
        }
#pragma unroll
        for (int t = 0; t < 4; t++) {
            int idx = tid + t * 256;          // 0..1023
            int r = idx >> 3, kb = (idx & 7) * 8;
            *(half8*)&Bs[r][kb] = *(const half8*)(BT + (size_t)r * K + k0 + kb);
        }
        __syncthreads();
#pragma unroll
        for (int kc = 0; kc < 2; kc++) {
            half8 a = *(const half8*)&As[wave * 16 + l16][kc * 32 + quad * 8];
#pragma unroll
            for (int j = 0; j < 8; j++) {
                half8 bb = *(const half8*)&Bs[j * 16 + l16][kc * 32 + quad * 8];
                acc[j] = __builtin_amdgcn_mfma_f32_16x16x32_f16(a, bb, acc[j], 0, 0, 0);
            }
        }
        __syncthreads();
    }

    float gj[8], bj[8], biasj[8];
#pragma unroll
    for (int j = 0; j < 8; j++) {
        int col = j * 16 + l16;
        biasj[j] = bias[col];
        gj[j] = g[col];
        bj[j] = b[col];
    }
    int row0 = mBase + wave * 16 + quad * 4;
    float sum[4] = {}, sq[4] = {};
#pragma unroll
    for (int r = 0; r < 4; r++) {
        int row = row0 + r;
        bool ok = row < M;
        size_t base = (size_t)row * HDIM;
#pragma unroll
        for (int j = 0; j < 8; j++) {
            float v = acc[j][r] + biasj[j] + (ok ? R[base + j * 16 + l16] : 0.0f);
            acc[j][r] = v;
            sum[r] += v;
            sq[r] += v * v;
        }
    }
#pragma unroll
    for (int r = 0; r < 4; r++) {
#pragma unroll
        for (int off = 1; off < 16; off <<= 1) {
            sum[r] += __shfl_xor(sum[r], off);
            sq[r] += __shfl_xor(sq[r], off);
        }
    }
#pragma unroll
    for (int r = 0; r < 4; r++) {
        int row = row0 + r;
        if (row >= M) continue;
        size_t base = (size_t)row * HDIM;
        float mu = sum[r] * (1.0f / HDIM);
        float var = sq[r] * (1.0f / HDIM) - mu * mu;
        float invstd = rsqrtf(var + 1e-5f);
#pragma unroll
        for (int j = 0; j < 8; j++) {
            float o = (acc[j][r] - mu) * invstd * gj[j] + bj[j];
            C32[base + j * 16 + l16] = o;
            if (C16) C16[base + j * 16 + l16] = (_Float16)o;
        }
    }
}

// ---------------------------------------------------------------------------
// Fused FFN: C = LN(GELU(A@W1T + b1)@W2T + b2 + R) * g + b.
// A f16 [M][128]; W1T [256][128]; W2T [128][256]. BM=64, 4 waves.
// Mid lives in LDS f16; W1/W2 staged in halves through one 128x136 buffer.
// ---------------------------------------------------------------------------
__global__ __launch_bounds__(256) void ffn_fused(const _Float16* __restrict__ A,
                                                 const _Float16* __restrict__ W1T,
                                                 const float* __restrict__ b1,
                                                 const _Float16* __restrict__ W2T,
                                                 const float* __restrict__ b2,
                                                 const float* __restrict__ R,
                                                 const float* __restrict__ g,
                                                 const float* __restrict__ b,
                                                 float* __restrict__ C32,
                                                 _Float16* __restrict__ C16,
                                                 int M) {
    __shared__ _Float16 Ws[128][128 + 8];   // 34.8 KB staging (W1 halves, W2 k-chunks)
    __shared__ _Float16 Mid[64][256 + 8];   // 33.8 KB (pad 8 -> 2-way LDS, free)
    int tid = threadIdx.x;
    int wave = tid >> 6, lane = tid & 63;
    int quad = lane >> 4, l16 = lane & 15;
    int mBase = blockIdx.x * 64;

    // A fragments direct from global (K=128): row = mBase + wave*16 + l16
    half8 afrag[4];
    {
        int row = mBase + wave * 16 + l16;
#pragma unroll
        for (int kc = 0; kc < 4; kc++) {
            if (row < M)
                afrag[kc] = *(const half8*)(A + (size_t)row * HDIM + kc * 32 + quad * 8);
            else
                afrag[kc] = (half8)(_Float16)0.0f;
        }
    }

    // ---- ffn1 + GELU: two mid halves of 128 cols ----
#pragma unroll
    for (int h = 0; h < 2; h++) {
        if (h) __syncthreads();   // Ws reused
#pragma unroll
        for (int t = 0; t < 8; t++) {
            int idx = tid + t * 256;          // 0..2047
            int r = idx >> 4, kb = (idx & 15) * 8;
            *(half8*)&Ws[r][kb] = *(const half8*)(W1T + (size_t)(h * 128 + r) * HDIM + kb);
        }
        __syncthreads();
        f32x4 acc[8] = {};
#pragma unroll
        for (int kc = 0; kc < 4; kc++) {
#pragma unroll
            for (int j = 0; j < 8; j++) {
                half8 bb = *(const half8*)&Ws[j * 16 + l16][kc * 32 + quad * 8];
                acc[j] = __builtin_amdgcn_mfma_f32_16x16x32_f16(afrag[kc], bb, acc[j], 0, 0, 0);
            }
        }
#pragma unroll
        for (int j = 0; j < 8; j++) {
            float bj1 = b1[h * 128 + j * 16 + l16];
#pragma unroll
            for (int r = 0; r < 4; r++) {
                float v = acc[j][r] + bj1;
                v = 0.5f * v * (1.0f + erff(v * 0.70710678118654752f));
                Mid[wave * 16 + quad * 4 + r][h * 128 + j * 16 + l16] = (_Float16)v;
            }
        }
    }
    __syncthreads();

    // ---- ffn2: K=256 in two 128-chunks ----
    f32x4 acc2[8] = {};
#pragma unroll
    for (int kc2 = 0; kc2 < 2; kc2++) {
        if (kc2) __syncthreads();
#pragma unroll
        for (int t = 0; t < 8; t++) {
            int idx = tid + t * 256;
            int r = idx >> 4, kb = (idx & 15) * 8;
            *(half8*)&Ws[r][kb] = *(const half8*)(W2T + (size_t)r * FFH + kc2 * 128 + kb);
        }
        __syncthreads();
#pragma unroll
        for (int kc = 0; kc < 4; kc++) {
            half8 am = *(const half8*)&Mid[wave * 16 + l16][kc2 * 128 + kc * 32 + quad * 8];
#pragma unroll
            for (int j = 0; j < 8; j++) {
                half8 bb = *(const half8*)&Ws[j * 16 + l16][kc * 32 + quad * 8];
                acc2[j] = __builtin_amdgcn_mfma_f32_16x16x32_f16(am, bb, acc2[j], 0, 0, 0);
            }
        }
    }

    // ---- epilogue: bias + residual + register LN ----
    float gj[8], bj[8], b2j[8];
#pragma unroll
    for (int j = 0; j < 8; j++) {
        int col = j * 16 + l16;
        b2j[j] = b2[col];
        gj[j] = g[col];
        bj[j] = b[col];
    }
    int row0 = mBase + wave * 16 + quad * 4;
    float sum[4] = {}, sq[4] = {};
#pragma unroll
    for (int r = 0; r < 4; r++) {
        int row = row0 + r;
        bool ok = row < M;
        size_t base = (size_t)row * HDIM;
#pragma unroll
        for (int j = 0; j < 8; j++) {
            float v = acc2[j][r] + b2j[j] + (ok ? R[base + j * 16 + l16] : 0.0f);
            acc2[j][r] = v;
            sum[r] += v;
            sq[r] += v * v;
        }
    }
#pragma unroll
    for (int r = 0; r < 4; r++) {
#pragma unroll
        for (int off = 1; off < 16; off <<= 1) {
            sum[r] += __shfl_xor(sum[r], off);
            sq[r] += __shfl_xor(sq[r], off);
        }
    }
#pragma unroll
    for (int r = 0; r < 4; r++) {
        int row = row0 + r;
        if (row >= M) continue;
        size_t base = (size_t)row * HDIM;
        float mu = sum[r] * (1.0f / HDIM);
        float var = sq[r] * (1.0f / HDIM) - mu * mu;
        float invstd = rsqrtf(var + 1e-5f);
#pragma unroll
        for (int j = 0; j < 8; j++) {
            float o = (acc2[j][r] - mu) * invstd * gj[j] + bj[j];
            C32[base + j * 16 + l16] = o;
            if (C16) C16[base + j * 16 + l16] = (_Float16)o;
        }
    }
}

// ---------------------------------------------------------------------------
// GATv2 attention + aggregation, packed-f16 math, one wave per dst node,
// online softmax, 2-edge unroll. XLR: [n][1024] f16 (XL 0..511, XR 512..1023).
// Concat: writes f16 into XR half. Non-concat: head-mean + bias + residual R
// + LayerNorm fused, dual write OUT32/OUT16h.
// ---------------------------------------------------------------------------
__global__ __launch_bounds__(256) void gat_edge_kernel(
    const _Float16* __restrict__ XLR,
    const int* __restrict__ row_ptr, const Edge* __restrict__ csr,
    const float* __restrict__ We,    // [2,512]
    const float* __restrict__ attW,  // [512]
    const float* __restrict__ cbias, // [512] or [128]
    _Float16* __restrict__ OUT16, float* __restrict__ OUT32,
    const float* __restrict__ R, const float* __restrict__ lng,
    const float* __restrict__ lnb, _Float16* __restrict__ OUT16h,
    int n, int concat) {
    int tid = threadIdx.x;
    int wave = tid >> 6, lane = tid & 63;
    int node = blockIdx.x * 4 + wave;
    if (node >= n) return;
    int c0 = lane * 8;

    h8 xr8 = *(const h8*)(XLR + (size_t)node * 1024 + 512 + c0);
    h8 w08, w18, att8;
#pragma unroll
    for (int k = 0; k < 8; k++) {
        w08[k] = (_Float16)We[c0 + k];
        w18[k] = (_Float16)We[HH + c0 + k];
        att8[k] = (_Float16)attW[c0 + k];
    }
    const _Float16 slope = (_Float16)NEG_SLOPE;

    h8 acc2 = (h8)(_Float16)0.0f;
    float m = -INFINITY, l = 0.0f;
    int beg = row_ptr[node], end = row_ptr[node + 1];
    int j = beg;
    for (; j + 1 < end; j += 2) {
        Edge e0 = csr[j], e1 = csr[j + 1];
        h8 x0 = *(const h8*)(XLR + (size_t)e0.src * 1024 + c0);
        h8 x1 = *(const h8*)(XLR + (size_t)e1.src * 1024 + c0);
        h8 v0 = x0 + (xr8 + w08 * e0.ea0 + w18 * e0.ea1);
        h8 v1 = x1 + (xr8 + w08 * e1.ea0 + w18 * e1.ea1);
        v0 = __builtin_elementwise_max(v0, v0 * slope);
        v1 = __builtin_elementwise_max(v1, v1 * slope);
        float p0 = hsum8(v0 * att8);
        float p1 = hsum8(v1 * att8);
        p0 += __shfl_xor(p0, 1); p1 += __shfl_xor(p1, 1);
        p0 += __shfl_xor(p0, 2); p1 += __shfl_xor(p1, 2);
        p0 += __shfl_xor(p0, 4); p1 += __shfl_xor(p1, 4);
        p0 += __shfl_xor(p0, 8); p1 += __shfl_xor(p1, 8);
        float mnew = fmaxf(m, fmaxf(p0, p1));
        float sc = __expf(m - mnew);
        float e0f = __expf(p0 - mnew);
        float e1f = __expf(p1 - mnew);
        l = l * sc + e0f + e1f;
        acc2 = acc2 * (_Float16)sc + x0 * (_Float16)e0f + x1 * (_Float16)e1f;
        m = mnew;
    }
    if (j < end) {
        Edge e0 = csr[j];
        h8 x0 = *(const h8*)(XLR + (size_t)e0.src * 1024 + c0);
        h8 v0 = x0 + (xr8 + w08 * e0.ea0 + w18 * e0.ea1);
        v0 = __builtin_elementwise_max(v0, v0 * slope);
        float p0 = hsum8(v0 * att8);
        p0 += __shfl_xor(p0, 1);
        p0 += __shfl_xor(p0, 2);
        p0 += __shfl_xor(p0, 4);
        p0 += __shfl_xor(p0, 8);
        float mnew = fmaxf(m, p0);
        float sc = __expf(m - mnew);
        float e0f = __expf(p0 - mnew);
        l = l * sc + e0f;
        acc2 = acc2 * (_Float16)sc + x0 * (_Float16)e0f;
        m = mnew;
    }
    float invf = 1.0f / (l + 1e-16f);
    if (concat) {
        h8 o = acc2 * (_Float16)invf;
#pragma unroll
        for (int k = 0; k < 8; k++) o[k] = o[k] + (_Float16)cbias[c0 + k];
        *(h8*)(OUT16 + (size_t)node * 1024 + c0) = o;
    } else {
        // head-mean: reduce across the 4 head groups (lanes +16,+32)
        float o8[8];
#pragma unroll
        for (int k = 0; k < 8; k++) {
            float a = (float)acc2[k] * invf;
            a += __shfl_xor(a, 16);
            a += __shfl_xor(a, 32);
            o8[k] = a;
        }
        // fused +bias +residual + LayerNorm over 128 ch held by lanes 0..15
        float v8[8];
        float sum = 0.0f, sq = 0.0f;
        if (lane < 16) {
#pragma unroll
            for (int k = 0; k < 8; k++) {
                float v = o8[k] * 0.25f + cbias[c0 + k] + R[(size_t)node * HDIM + c0 + k];
                v8[k] = v;
                sum += v;
                sq += v * v;
            }
        }
#pragma unroll
        for (int off = 1; off < 16; off <<= 1) {
            sum += __shfl_xor(sum, off);
            sq += __shfl_xor(sq, off);
        }
        if (lane < 16) {
            float mu = sum * (1.0f / HDIM);
            float var = sq * (1.0f / HDIM) - mu * mu;
            float invstd = rsqrtf(var + 1e-5f);
#pragma unroll
            for (int k = 0; k < 8; k++) {
                float o = (v8[k] - mu) * invstd * lng[c0 + k] + lnb[c0 + k];
                OUT32[(size_t)node * HDIM + c0 + k] = o;
                OUT16h[(size_t)node * HDIM + c0 + k] = (_Float16)o;
            }
        }
    }
}

// ---------------------------------------------------------------------------
extern "C" void kernel_launch(void* const* d_in, const int* in_sizes, int n_in,
                              void* d_out, int out_size, void* d_ws, size_t ws_size,
                              hipStream_t stream) {
    const float* x        = (const float*)d_in[0];
    const int*   ei       = (const int*)d_in[1];
    const float* eattr    = (const float*)d_in[2];
    const float* emb_w    = (const float*)d_in[3];
    const float* emb_b    = (const float*)d_in[4];
    const float* lin_l    = (const float*)d_in[5];
    const float* lin_r    = (const float*)d_in[6];
    const float* lin_edge = (const float*)d_in[7];
    const float* attw     = (const float*)d_in[8];
    const float* cb01     = (const float*)d_in[9];
    const float* cb2      = (const float*)d_in[10];
    const float* proj_w   = (const float*)d_in[11];
    const float* proj_b   = (const float*)d_in[12];
    const float* n1g      = (const float*)d_in[13];
    const float* n1b      = (const float*)d_in[14];
    const float* n2g      = (const float*)d_in[15];
    const float* n2b      = (const float*)d_in[16];
    const float* fw1      = (const float*)d_in[17];
    const float* fb1      = (const float*)d_in[18];
    const float* fw2      = (const float*)d_in[19];
    const float* fb2      = (const float*)d_in[20];
    float* out = (float*)d_out;

    const int n = in_sizes[0] / IN_DIM;   // 20000
    const int E = in_sizes[2] / 2;        // 320000
    const int EP = E + n;

    size_t off = 0;
    auto alloc = [&](size_t bytes) {
        void* p = (char*)d_ws + off;
        off += (bytes + 255) & ~(size_t)255;
        return p;
    };
    float* deg     = (float*)alloc((size_t)n * 4);
    float* asum    = (float*)alloc((size_t)2 * n * 4);
    int*   row_ptr = (int*)alloc((size_t)(n + 1) * 4);
    int*   cur     = (int*)alloc((size_t)n * 4);
    Edge*  csr     = (Edge*)alloc((size_t)EP * 8);
    float* H0      = (float*)alloc((size_t)n * HDIM * 4);
    float* H1      = (float*)alloc((size_t)n * HDIM * 4);
    _Float16* H0h  = (_Float16*)alloc((size_t)n * HDIM * 2);
    _Float16* H1h  = (_Float16*)alloc((size_t)n * HDIM * 2);
    _Float16* XLR  = (_Float16*)alloc((size_t)n * 1024 * 2);
    _Float16* xh   = (_Float16*)alloc((size_t)n * 64 * 2);
    _Float16* wt_emb  = (_Float16*)alloc((size_t)HDIM * 64 * 2);
    _Float16* wt_llr  = (_Float16*)alloc((size_t)3 * 1024 * HDIM * 2);
    _Float16* wt_proj = (_Float16*)alloc((size_t)2 * HDIM * HH * 2);
    _Float16* wt_f1   = (_Float16*)alloc((size_t)3 * FFH * HDIM * 2);
    _Float16* wt_f2   = (_Float16*)alloc((size_t)3 * HDIM * FFH * 2);
    (void)ws_size;

    // ---- input prep ----
    xpad_kernel<<<(n * 64 + 255) / 256, 256, 0, stream>>>(x, xh, n);
    WDescs ds;
    int di = 0;
    ds.d[di++] = {emb_w, wt_emb, IN_DIM, 6, 7};
    for (int i = 0; i < 3; i++) {
        ds.d[di++] = {lin_l + (size_t)i * HDIM * HH, wt_llr + (size_t)i * 1024 * HDIM, HDIM, 7, 9};
        ds.d[di++] = {lin_r + (size_t)i * HDIM * HH, wt_llr + (size_t)i * 1024 * HDIM + (size_t)512 * HDIM, HDIM, 7, 9};
    }
    for (int i = 0; i < 2; i++)
        ds.d[di++] = {proj_w + (size_t)i * HH * HDIM, wt_proj + (size_t)i * HDIM * HH, HH, 9, 7};
    for (int i = 0; i < 3; i++)
        ds.d[di++] = {fw1 + (size_t)i * HDIM * FFH, wt_f1 + (size_t)i * FFH * HDIM, HDIM, 7, 8};
    for (int i = 0; i < 3; i++)
        ds.d[di++] = {fw2 + (size_t)i * FFH * HDIM, wt_f2 + (size_t)i * HDIM * FFH, FFH, 8, 7};
    wconv_kernel<<<dim3(32, 15), 256, 0, stream>>>(ds);

    // ---- CSR build ----
    (void)hipMemsetAsync(deg, 0, (size_t)n * 4, stream);
    (void)hipMemsetAsync(asum, 0, (size_t)2 * n * 4, stream);
    deg_kernel<<<(E + 255) / 256, 256, 0, stream>>>(ei, eattr, deg, asum, E);
    scan_kernel<<<1, 1024, 0, stream>>>(deg, row_ptr, cur, n);
    scatter_kernel<<<(EP + 255) / 256, 256, 0, stream>>>(ei, eattr, deg, asum, cur, csr, E, n);

    // ---- Embedding: H0(+H0h) = xh @ wt_emb + emb_b ----
    gemm_mfma<2, 128><<<dim3(1, (n + 127) / 128), 256, 0, stream>>>(
        xh, 64, wt_emb, emb_b, H0, H0h, n, HDIM, 64);

    // ---- 3 GATv2 + FFN layers ----
    for (int i = 0; i < 3; i++) {
        int concat = (i < 2);
        // fused lin_l|lin_r: XLR[n][1024]
        gemm_mfma<1, 128><<<dim3(8, (n + 127) / 128), 256, 0, stream>>>(
            H0h, HDIM, wt_llr + (size_t)i * 1024 * HDIM, nullptr, nullptr, XLR, n, 1024, HDIM);
        // gat: concat -> f16 into XR half; non-concat -> fused mean+bias+res+LN
        gat_edge_kernel<<<(n + 3) / 4, 256, 0, stream>>>(
            XLR, row_ptr, csr,
            lin_edge + (size_t)i * 2 * HH, attw + (size_t)i * HH,
            concat ? (cb01 + (size_t)i * HH) : cb2,
            XLR + 512, H1,
            H0, n1g + (size_t)i * HDIM, n1b + (size_t)i * HDIM, H1h,
            n, concat);
        if (concat) {
            // H1,H1h = LN(proj(gatout) + pb + H0)
            gemm_ln<<<(n + 63) / 64, 256, 0, stream>>>(
                XLR + 512, 1024, wt_proj + (size_t)i * HDIM * HH,
                proj_b + (size_t)i * HDIM, H0,
                n1g + (size_t)i * HDIM, n1b + (size_t)i * HDIM,
                H1, H1h, n, HH);
        }
        // {out|H0,H0h} = LN(GELU(H1h@W1+b1)@W2 + b2 + H1)
        float* lnout = (i == 2) ? out : H0;
        _Float16* lnout16 = (i == 2) ? nullptr : H0h;
        ffn_fused<<<(n + 63) / 64, 256, 0, stream>>>(
            H1h, wt_f1 + (size_t)i * FFH * HDIM, fb1 + (size_t)i * FFH,
            wt_f2 + (size_t)i * HDIM * FFH, fb2 + (size_t)i * HDIM, H1,
            n2g + (size_t)i * HDIM, n2b + (size_t)i * HDIM,
            lnout, lnout16, n);
    }
}

// Round 9
// 568.667 us; speedup vs baseline: 1.2728x; 1.0555x over previous
//
#include <hip/hip_runtime.h>
#include <math.h>

#define IN_DIM 16
#define HDIM   128
#define HEADS  4
#define HH     512   // HEADS*HDIM
#define FFH    256   // 2*HDIM
#define NEG_SLOPE 0.2f

typedef _Float16 half8 __attribute__((ext_vector_type(8)));
typedef _Float16 h8 __attribute__((ext_vector_type(8)));
typedef _Float16 h4 __attribute__((ext_vector_type(4)));
typedef _Float16 h2 __attribute__((ext_vector_type(2)));
typedef float f32x4 __attribute__((ext_vector_type(4)));

struct __align__(8) Edge { int src; _Float16 ea0, ea1; };

static __device__ inline float hsum8(h8 v) {
    h4 a = __builtin_shufflevector(v, v, 0, 1, 2, 3) +
           __builtin_shufflevector(v, v, 4, 5, 6, 7);
    h2 b = __builtin_shufflevector(a, a, 0, 1) +
           __builtin_shufflevector(a, a, 2, 3);
    return (float)b[0] + (float)b[1];
}

// ---------------------------------------------------------------------------
// x pad: xh[n][64] = f16(x[n][16]) zero-padded
// ---------------------------------------------------------------------------
__global__ void xpad_kernel(const float* __restrict__ x, _Float16* __restrict__ xh, int n) {
    int idx = blockIdx.x * 256 + threadIdx.x;
    if (idx >= n * 64) return;
    int r = idx >> 6, k = idx & 63;
    xh[idx] = (k < IN_DIM) ? (_Float16)x[r * IN_DIM + k] : (_Float16)0.0f;
}

// ---------------------------------------------------------------------------
// Weight convert+transpose+K-pad: W[Ksrc][N] fp32 -> WT[N][Kd] f16 (zero pad)
// ---------------------------------------------------------------------------
struct WDesc { const float* src; _Float16* dst; int Ksrc; int lgKd; int lgN; };
struct WDescs { WDesc d[15]; };
__global__ void wconv_kernel(WDescs ds) {
    WDesc w = ds.d[blockIdx.y];
    int Kd = 1 << w.lgKd;
    int total = 1 << (w.lgKd + w.lgN);
    for (int idx = blockIdx.x * 256 + threadIdx.x; idx < total; idx += gridDim.x * 256) {
        int n2 = idx >> w.lgKd, k = idx & (Kd - 1);
        w.dst[idx] = (k < w.Ksrc) ? (_Float16)w.src[(k << w.lgN) + n2] : (_Float16)0.0f;
    }
}

// ---------------------------------------------------------------------------
// Preprocess: degree + edge_attr sums (self-loop fill_value='mean')
// ---------------------------------------------------------------------------
__global__ void deg_kernel(const int* __restrict__ ei, const float* __restrict__ eattr,
                           float* deg, float* asum, int E) {
    int e = blockIdx.x * blockDim.x + threadIdx.x;
    if (e >= E) return;
    int d = ei[E + e];
    atomicAdd(&deg[d], 1.0f);
    atomicAdd(&asum[2 * d], eattr[2 * e]);
    atomicAdd(&asum[2 * d + 1], eattr[2 * e + 1]);
}

__global__ void scan_kernel(const float* __restrict__ deg, int* row_ptr, int* cur, int n) {
    __shared__ int sums[1024];
    int tid = threadIdx.x;
    int per = (n + 1023) / 1024;
    int s0 = tid * per;
    int s1 = s0 + per; if (s1 > n) s1 = n;
    int s = 0;
    for (int i = s0; i < s1; i++) s += (int)deg[i] + 1;
    int mysum = s;
    sums[tid] = s;
    __syncthreads();
    for (int dd = 1; dd < 1024; dd <<= 1) {
        int t = (tid >= dd) ? sums[tid - dd] : 0;
        __syncthreads();
        sums[tid] += t;
        __syncthreads();
    }
    int run = sums[tid] - mysum;   // exclusive prefix
    for (int i = s0; i < s1; i++) {
        row_ptr[i] = run; cur[i] = run;
        run += (int)deg[i] + 1;
    }
    if (tid == 1023) row_ptr[n] = sums[1023];
}

__global__ void scatter_kernel(const int* __restrict__ ei, const float* __restrict__ eattr,
                               const float* __restrict__ deg, const float* __restrict__ asum,
                               int* cur, Edge* csr, int E, int n) {
    int i = blockIdx.x * blockDim.x + threadIdx.x;
    if (i >= E + n) return;
    Edge ed;
    int pos;
    if (i < E) {
        int d = ei[E + i];
        pos = atomicAdd(&cur[d], 1);
        ed.src = ei[i];
        ed.ea0 = (_Float16)eattr[2 * i];
        ed.ea1 = (_Float16)eattr[2 * i + 1];
    } else {
        int nd = i - E;
        float dv = fmaxf(deg[nd], 1.0f);
        pos = atomicAdd(&cur[nd], 1);
        ed.src = nd;
        ed.ea0 = (_Float16)(asum[2 * nd] / dv);
        ed.ea1 = (_Float16)(asum[2 * nd + 1] / dv);
    }
    csr[pos] = ed;
}

// ---------------------------------------------------------------------------
// B-stationary MFMA GEMM for K<=128: BT column-slice staged in LDS ONCE,
// B-fragments hoisted to registers, then barrier-free grid-stride loop over
// 64-row M-tiles with A-fragments loaded directly from global.
// 4 waves in 2x2: wave = 32 rows x 64 cols. KT in {64,128}.
// OUTMODE: 1=f16 only, 2=f32+f16. Nstride = output row stride.
// ---------------------------------------------------------------------------
template <int KT, int OUTMODE>
__global__ __launch_bounds__(256) void gemm_bstat(const _Float16* __restrict__ A, int lda,
                                                  const _Float16* __restrict__ BT,
                                                  const float* __restrict__ bias,
                                                  float* __restrict__ C32,
                                                  _Float16* __restrict__ C16,
                                                  int M, int Nstride, int numMT) {
    const int PAD = 8, KC = KT / 32;
    __shared__ _Float16 Bs[128][KT + PAD];
    int tid = threadIdx.x;
    int wave = tid >> 6, lane = tid & 63;
    int quad = lane >> 4, l16 = lane & 15;
    int wrow = (wave >> 1) * 32, wcol = (wave & 1) * 64;
    int n0 = blockIdx.x * 128;

    // ---- stage BT[n0..n0+128][0..KT] (once) ----
#pragma unroll
    for (int t = 0; t < KT / 16; t++) {
        int idx = tid + t * 256;
        int r = idx / (KT / 8), kb = (idx % (KT / 8)) * 8;
        *(half8*)&Bs[r][kb] = *(const half8*)(BT + (size_t)(n0 + r) * KT + kb);
    }
    __syncthreads();

    // ---- hoist B fragments to registers ----
    half8 bfrag[4][KC];
#pragma unroll
    for (int j = 0; j < 4; j++)
#pragma unroll
        for (int kc = 0; kc < KC; kc++)
            bfrag[j][kc] = *(const half8*)&Bs[wcol + j * 16 + l16][kc * 32 + quad * 8];

    float biasj[4];
#pragma unroll
    for (int j = 0; j < 4; j++)
        biasj[j] = bias ? bias[n0 + wcol + j * 16 + l16] : 0.0f;

    // ---- barrier-free M loop ----
    for (int mt = blockIdx.y; mt < numMT; mt += gridDim.y) {
        int rbase = mt * 64 + wrow;
        half8 af[2][KC];
#pragma unroll
        for (int i = 0; i < 2; i++) {
            int row = rbase + i * 16 + l16;
#pragma unroll
            for (int kc = 0; kc < KC; kc++)
                af[i][kc] = (row < M) ? *(const half8*)(A + (size_t)row * lda + kc * 32 + quad * 8)
                                      : (half8)(_Float16)0.0f;
        }
        f32x4 acc[2][4] = {};
#pragma unroll
        for (int kc = 0; kc < KC; kc++)
#pragma unroll
            for (int i = 0; i < 2; i++)
#pragma unroll
                for (int j = 0; j < 4; j++)
                    acc[i][j] = __builtin_amdgcn_mfma_f32_16x16x32_f16(af[i][kc], bfrag[j][kc], acc[i][j], 0, 0, 0);
#pragma unroll
        for (int i = 0; i < 2; i++) {
#pragma unroll
            for (int r = 0; r < 4; r++) {
                int row = rbase + i * 16 + quad * 4 + r;
                if (row >= M) continue;
#pragma unroll
                for (int j = 0; j < 4; j++) {
                    int col = n0 + wcol + j * 16 + l16;
                    float v = acc[i][j][r] + biasj[j];
                    if (OUTMODE == 2)
                        C32[(size_t)row * Nstride + col] = v;
                    C16[(size_t)row * Nstride + col] = (_Float16)v;
                }
            }
        }
    }
}

// ---------------------------------------------------------------------------
// Fused GEMM(+bias) + residual + LayerNorm for N=128, register-resident LN.
// C = LN(A@BT + bias + R) * g + b; dual write f32 (+f16 if C16).
// BM=64, 4 waves; wave covers 16 rows x 128 cols.
// ---------------------------------------------------------------------------
__global__ __launch_bounds__(256) void gemm_ln(const _Float16* __restrict__ A, int lda,
                                               const _Float16* __restrict__ BT,
                                               const float* __restrict__ bias,
                                               const float* __restrict__ R,
                                               const float* __restrict__ g,
                                               const float* __restrict__ b,
                                               float* __restrict__ C32,
                                               _Float16* __restrict__ C16,
                                               int M, int K) {
    const int BK = 64, PAD = 8;
    __shared__ _Float16 As[64][BK + PAD];
    __shared__ _Float16 Bs[128][BK + PAD];
    int tid = threadIdx.x;
    int wave = tid >> 6, lane = tid & 63;
    int quad = lane >> 4, l16 = lane & 15;
    int mBase = blockIdx.x * 64;

    f32x4 acc[8] = {};

    for (int k0 = 0; k0 < K; k0 += BK) {
#pragma unroll
        for (int t = 0; t < 2; t++) {
            int idx = tid + t * 256;          // 0..511
            int r = idx >> 3, kb = (idx & 7) * 8;
            half8 hv = {};
            int grow = mBase + r;
            if (grow < M) hv = *(const half8*)(A + (size_t)grow * lda + k0 + kb);
            *(half8*)&As[r][kb] = hv;
        }
#pragma unroll
        for (int t = 0; t < 4; t++) {
            int idx = tid + t * 256;          // 0..1023
            int r = idx >> 3, kb = (idx & 7) * 8;
            *(half8*)&Bs[r][kb] = *(const half8*)(BT + (size_t)r * K + k0 + kb);
        }
        __syncthreads();
#pragma unroll
        for (int kc = 0; kc < 2; kc++) {
            half8 a = *(const half8*)&As[wave * 16 + l16][kc * 32 + quad * 8];
#pragma unroll
            for (int j = 0; j < 8; j++) {
                half8 bb = *(const half8*)&Bs[j * 16 + l16][kc * 32 + quad * 8];
                acc[j] = __builtin_amdgcn_mfma_f32_16x16x32_f16(a, bb, acc[j], 0, 0, 0);
            }
        }
        __syncthreads();
    }

    float gj[8], bj[8], biasj[8];
#pragma unroll
    for (int j = 0; j < 8; j++) {
        int col = j * 16 + l16;
        biasj[j] = bias[col];
        gj[j] = g[col];
        bj[j] = b[col];
    }
    int row0 = mBase + wave * 16 + quad * 4;
    float sum[4] = {}, sq[4] = {};
#pragma unroll
    for (int r = 0; r < 4; r++) {
        int row = row0 + r;
        bool ok = row < M;
        size_t base = (size_t)row * HDIM;
#pragma unroll
        for (int j = 0; j < 8; j++) {
            float v = acc[j][r] + biasj[j] + (ok ? R[base + j * 16 + l16] : 0.0f);
            acc[j][r] = v;
            sum[r] += v;
            sq[r] += v * v;
        }
    }
#pragma unroll
    for (int r = 0; r < 4; r++) {
#pragma unroll
        for (int off = 1; off < 16; off <<= 1) {
            sum[r] += __shfl_xor(sum[r], off);
            sq[r] += __shfl_xor(sq[r], off);
        }
    }
#pragma unroll
    for (int r = 0; r < 4; r++) {
        int row = row0 + r;
        if (row >= M) continue;
        size_t base = (size_t)row * HDIM;
        float mu = sum[r] * (1.0f / HDIM);
        float var = sq[r] * (1.0f / HDIM) - mu * mu;
        float invstd = rsqrtf(var + 1e-5f);
#pragma unroll
        for (int j = 0; j < 8; j++) {
            float o = (acc[j][r] - mu) * invstd * gj[j] + bj[j];
            C32[base + j * 16 + l16] = o;
            if (C16) C16[base + j * 16 + l16] = (_Float16)o;
        }
    }
}

// ---------------------------------------------------------------------------
// Fused FFN: C = LN(GELU(A@W1T + b1)@W2T + b2 + R) * g + b.
// A f16 [M][128]; W1T [256][128]; W2T [128][256]. BM=64, 4 waves.
// ---------------------------------------------------------------------------
__global__ __launch_bounds__(256) void ffn_fused(const _Float16* __restrict__ A,
                                                 const _Float16* __restrict__ W1T,
                                                 const float* __restrict__ b1,
                                                 const _Float16* __restrict__ W2T,
                                                 const float* __restrict__ b2,
                                                 const float* __restrict__ R,
                                                 const float* __restrict__ g,
                                                 const float* __restrict__ b,
                                                 float* __restrict__ C32,
                                                 _Float16* __restrict__ C16,
                                                 int M) {
    __shared__ _Float16 Ws[128][128 + 8];
    __shared__ _Float16 Mid[64][256 + 8];
    int tid = threadIdx.x;
    int wave = tid >> 6, lane = tid & 63;
    int quad = lane >> 4, l16 = lane & 15;
    int mBase = blockIdx.x * 64;

    half8 afrag[4];
    {
        int row = mBase + wave * 16 + l16;
#pragma unroll
        for (int kc = 0; kc < 4; kc++) {
            if (row < M)
                afrag[kc] = *(const half8*)(A + (size_t)row * HDIM + kc * 32 + quad * 8);
            else
                afrag[kc] = (half8)(_Float16)0.0f;
        }
    }

#pragma unroll
    for (int h = 0; h < 2; h++) {
        if (h) __syncthreads();
#pragma unroll
        for (int t = 0; t < 8; t++) {
            int idx = tid + t * 256;
            int r = idx >> 4, kb = (idx & 15) * 8;
            *(half8*)&Ws[r][kb] = *(const half8*)(W1T + (size_t)(h * 128 + r) * HDIM + kb);
        }
        __syncthreads();
        f32x4 acc[8] = {};
#pragma unroll
        for (int kc = 0; kc < 4; kc++) {
#pragma unroll
            for (int j = 0; j < 8; j++) {
                half8 bb = *(const half8*)&Ws[j * 16 + l16][kc * 32 + quad * 8];
                acc[j] = __builtin_amdgcn_mfma_f32_16x16x32_f16(afrag[kc], bb, acc[j], 0, 0, 0);
            }
        }
#pragma unroll
        for (int j = 0; j < 8; j++) {
            float bj1 = b1[h * 128 + j * 16 + l16];
#pragma unroll
            for (int r = 0; r < 4; r++) {
                float v = acc[j][r] + bj1;
                v = 0.5f * v * (1.0f + erff(v * 0.70710678118654752f));
                Mid[wave * 16 + quad * 4 + r][h * 128 + j * 16 + l16] = (_Float16)v;
            }
        }
    }
    __syncthreads();

    f32x4 acc2[8] = {};
#pragma unroll
    for (int kc2 = 0; kc2 < 2; kc2++) {
        if (kc2) __syncthreads();
#pragma unroll
        for (int t = 0; t < 8; t++) {
            int idx = tid + t * 256;
            int r = idx >> 4, kb = (idx & 15) * 8;
            *(half8*)&Ws[r][kb] = *(const half8*)(W2T + (size_t)r * FFH + kc2 * 128 + kb);
        }
        __syncthreads();
#pragma unroll
        for (int kc = 0; kc < 4; kc++) {
            half8 am = *(const half8*)&Mid[wave * 16 + l16][kc2 * 128 + kc * 32 + quad * 8];
#pragma unroll
            for (int j = 0; j < 8; j++) {
                half8 bb = *(const half8*)&Ws[j * 16 + l16][kc * 32 + quad * 8];
                acc2[j] = __builtin_amdgcn_mfma_f32_16x16x32_f16(am, bb, acc2[j], 0, 0, 0);
            }
        }
    }

    float gj[8], bj[8], b2j[8];
#pragma unroll
    for (int j = 0; j < 8; j++) {
        int col = j * 16 + l16;
        b2j[j] = b2[col];
        gj[j] = g[col];
        bj[j] = b[col];
    }
    int row0 = mBase + wave * 16 + quad * 4;
    float sum[4] = {}, sq[4] = {};
#pragma unroll
    for (int r = 0; r < 4; r++) {
        int row = row0 + r;
        bool ok = row < M;
        size_t base = (size_t)row * HDIM;
#pragma unroll
        for (int j = 0; j < 8; j++) {
            float v = acc2[j][r] + b2j[j] + (ok ? R[base + j * 16 + l16] : 0.0f);
            acc2[j][r] = v;
            sum[r] += v;
            sq[r] += v * v;
        }
    }
#pragma unroll
    for (int r = 0; r < 4; r++) {
#pragma unroll
        for (int off = 1; off < 16; off <<= 1) {
            sum[r] += __shfl_xor(sum[r], off);
            sq[r] += __shfl_xor(sq[r], off);
        }
    }
#pragma unroll
    for (int r = 0; r < 4; r++) {
        int row = row0 + r;
        if (row >= M) continue;
        size_t base = (size_t)row * HDIM;
        float mu = sum[r] * (1.0f / HDIM);
        float var = sq[r] * (1.0f / HDIM) - mu * mu;
        float invstd = rsqrtf(var + 1e-5f);
#pragma unroll
        for (int j = 0; j < 8; j++) {
            float o = (acc2[j][r] - mu) * invstd * gj[j] + bj[j];
            C32[base + j * 16 + l16] = o;
            if (C16) C16[base + j * 16 + l16] = (_Float16)o;
        }
    }
}

// ---------------------------------------------------------------------------
// GATv2 attention + aggregation, packed-f16 math, one wave per dst node,
// online softmax, 2-edge unroll. XLR: [n][1024] f16 (XL 0..511, XR 512..1023).
// Concat: writes f16 into XR half. Non-concat: head-mean + bias + residual R
// + LayerNorm fused, dual write OUT32/OUT16h.
// ---------------------------------------------------------------------------
__global__ __launch_bounds__(256) void gat_edge_kernel(
    const _Float16* __restrict__ XLR,
    const int* __restrict__ row_ptr, const Edge* __restrict__ csr,
    const float* __restrict__ We,    // [2,512]
    const float* __restrict__ attW,  // [512]
    const float* __restrict__ cbias, // [512] or [128]
    _Float16* __restrict__ OUT16, float* __restrict__ OUT32,
    const float* __restrict__ R, const float* __restrict__ lng,
    const float* __restrict__ lnb, _Float16* __restrict__ OUT16h,
    int n, int concat) {
    int tid = threadIdx.x;
    int wave = tid >> 6, lane = tid & 63;
    int node = blockIdx.x * 4 + wave;
    if (node >= n) return;
    int c0 = lane * 8;

    h8 xr8 = *(const h8*)(XLR + (size_t)node * 1024 + 512 + c0);
    h8 w08, w18, att8;
#pragma unroll
    for (int k = 0; k < 8; k++) {
        w08[k] = (_Float16)We[c0 + k];
        w18[k] = (_Float16)We[HH + c0 + k];
        att8[k] = (_Float16)attW[c0 + k];
    }
    const _Float16 slope = (_Float16)NEG_SLOPE;

    h8 acc2 = (h8)(_Float16)0.0f;
    float m = -INFINITY, l = 0.0f;
    int beg = row_ptr[node], end = row_ptr[node + 1];
    int j = beg;
    for (; j + 1 < end; j += 2) {
        Edge e0 = csr[j], e1 = csr[j + 1];
        h8 x0 = *(const h8*)(XLR + (size_t)e0.src * 1024 + c0);
        h8 x1 = *(const h8*)(XLR + (size_t)e1.src * 1024 + c0);
        h8 v0 = x0 + (xr8 + w08 * e0.ea0 + w18 * e0.ea1);
        h8 v1 = x1 + (xr8 + w08 * e1.ea0 + w18 * e1.ea1);
        v0 = __builtin_elementwise_max(v0, v0 * slope);
        v1 = __builtin_elementwise_max(v1, v1 * slope);
        float p0 = hsum8(v0 * att8);
        float p1 = hsum8(v1 * att8);
        p0 += __shfl_xor(p0, 1); p1 += __shfl_xor(p1, 1);
        p0 += __shfl_xor(p0, 2); p1 += __shfl_xor(p1, 2);
        p0 += __shfl_xor(p0, 4); p1 += __shfl_xor(p1, 4);
        p0 += __shfl_xor(p0, 8); p1 += __shfl_xor(p1, 8);
        float mnew = fmaxf(m, fmaxf(p0, p1));
        float sc = __expf(m - mnew);
        float e0f = __expf(p0 - mnew);
        float e1f = __expf(p1 - mnew);
        l = l * sc + e0f + e1f;
        acc2 = acc2 * (_Float16)sc + x0 * (_Float16)e0f + x1 * (_Float16)e1f;
        m = mnew;
    }
    if (j < end) {
        Edge e0 = csr[j];
        h8 x0 = *(const h8*)(XLR + (size_t)e0.src * 1024 + c0);
        h8 v0 = x0 + (xr8 + w08 * e0.ea0 + w18 * e0.ea1);
        v0 = __builtin_elementwise_max(v0, v0 * slope);
        float p0 = hsum8(v0 * att8);
        p0 += __shfl_xor(p0, 1);
        p0 += __shfl_xor(p0, 2);
        p0 += __shfl_xor(p0, 4);
        p0 += __shfl_xor(p0, 8);
        float mnew = fmaxf(m, p0);
        float sc = __expf(m - mnew);
        float e0f = __expf(p0 - mnew);
        l = l * sc + e0f;
        acc2 = acc2 * (_Float16)sc + x0 * (_Float16)e0f;
        m = mnew;
    }
    float invf = 1.0f / (l + 1e-16f);
    if (concat) {
        h8 o = acc2 * (_Float16)invf;
#pragma unroll
        for (int k = 0; k < 8; k++) o[k] = o[k] + (_Float16)cbias[c0 + k];
        *(h8*)(OUT16 + (size_t)node * 1024 + c0) = o;
    } else {
        float o8[8];
#pragma unroll
        for (int k = 0; k < 8; k++) {
            float a = (float)acc2[k] * invf;
            a += __shfl_xor(a, 16);
            a += __shfl_xor(a, 32);
            o8[k] = a;
        }
        float v8[8];
        float sum = 0.0f, sq = 0.0f;
        if (lane < 16) {
#pragma unroll
            for (int k = 0; k < 8; k++) {
                float v = o8[k] * 0.25f + cbias[c0 + k] + R[(size_t)node * HDIM + c0 + k];
                v8[k] = v;
                sum += v;
                sq += v * v;
            }
        }
#pragma unroll
        for (int off = 1; off < 16; off <<= 1) {
            sum += __shfl_xor(sum, off);
            sq += __shfl_xor(sq, off);
        }
        if (lane < 16) {
            float mu = sum * (1.0f / HDIM);
            float var = sq * (1.0f / HDIM) - mu * mu;
            float invstd = rsqrtf(var + 1e-5f);
#pragma unroll
            for (int k = 0; k < 8; k++) {
                float o = (v8[k] - mu) * invstd * lng[c0 + k] + lnb[c0 + k];
                OUT32[(size_t)node * HDIM + c0 + k] = o;
                OUT16h[(size_t)node * HDIM + c0 + k] = (_Float16)o;
            }
        }
    }
}

// ---------------------------------------------------------------------------
extern "C" void kernel_launch(void* const* d_in, const int* in_sizes, int n_in,
                              void* d_out, int out_size, void* d_ws, size_t ws_size,
                              hipStream_t stream) {
    const float* x        = (const float*)d_in[0];
    const int*   ei       = (const int*)d_in[1];
    const float* eattr    = (const float*)d_in[2];
    const float* emb_w    = (const float*)d_in[3];
    const float* emb_b    = (const float*)d_in[4];
    const float* lin_l    = (const float*)d_in[5];
    const float* lin_r    = (const float*)d_in[6];
    const float* lin_edge = (const float*)d_in[7];
    const float* attw     = (const float*)d_in[8];
    const float* cb01     = (const float*)d_in[9];
    const float* cb2      = (const float*)d_in[10];
    const float* proj_w   = (const float*)d_in[11];
    const float* proj_b   = (const float*)d_in[12];
    const float* n1g      = (const float*)d_in[13];
    const float* n1b      = (const float*)d_in[14];
    const float* n2g      = (const float*)d_in[15];
    const float* n2b      = (const float*)d_in[16];
    const float* fw1      = (const float*)d_in[17];
    const float* fb1      = (const float*)d_in[18];
    const float* fw2      = (const float*)d_in[19];
    const float* fb2      = (const float*)d_in[20];
    float* out = (float*)d_out;

    const int n = in_sizes[0] / IN_DIM;   // 20000
    const int E = in_sizes[2] / 2;        // 320000
    const int EP = E + n;
    const int numMT = (n + 63) / 64;

    size_t off = 0;
    auto alloc = [&](size_t bytes) {
        void* p = (char*)d_ws + off;
        off += (bytes + 255) & ~(size_t)255;
        return p;
    };
    float* deg     = (float*)alloc((size_t)n * 4);
    float* asum    = (float*)alloc((size_t)2 * n * 4);
    int*   row_ptr = (int*)alloc((size_t)(n + 1) * 4);
    int*   cur     = (int*)alloc((size_t)n * 4);
    Edge*  csr     = (Edge*)alloc((size_t)EP * 8);
    float* H0      = (float*)alloc((size_t)n * HDIM * 4);
    float* H1      = (float*)alloc((size_t)n * HDIM * 4);
    _Float16* H0h  = (_Float16*)alloc((size_t)n * HDIM * 2);
    _Float16* H1h  = (_Float16*)alloc((size_t)n * HDIM * 2);
    _Float16* XLR  = (_Float16*)alloc((size_t)n * 1024 * 2);
    _Float16* xh   = (_Float16*)alloc((size_t)n * 64 * 2);
    _Float16* wt_emb  = (_Float16*)alloc((size_t)HDIM * 64 * 2);
    _Float16* wt_llr  = (_Float16*)alloc((size_t)3 * 1024 * HDIM * 2);
    _Float16* wt_proj = (_Float16*)alloc((size_t)2 * HDIM * HH * 2);
    _Float16* wt_f1   = (_Float16*)alloc((size_t)3 * FFH * HDIM * 2);
    _Float16* wt_f2   = (_Float16*)alloc((size_t)3 * HDIM * FFH * 2);
    (void)ws_size;

    // ---- input prep ----
    xpad_kernel<<<(n * 64 + 255) / 256, 256, 0, stream>>>(x, xh, n);
    WDescs ds;
    int di = 0;
    ds.d[di++] = {emb_w, wt_emb, IN_DIM, 6, 7};
    for (int i = 0; i < 3; i++) {
        ds.d[di++] = {lin_l + (size_t)i * HDIM * HH, wt_llr + (size_t)i * 1024 * HDIM, HDIM, 7, 9};
        ds.d[di++] = {lin_r + (size_t)i * HDIM * HH, wt_llr + (size_t)i * 1024 * HDIM + (size_t)512 * HDIM, HDIM, 7, 9};
    }
    for (int i = 0; i < 2; i++)
        ds.d[di++] = {proj_w + (size_t)i * HH * HDIM, wt_proj + (size_t)i * HDIM * HH, HH, 9, 7};
    for (int i = 0; i < 3; i++)
        ds.d[di++] = {fw1 + (size_t)i * HDIM * FFH, wt_f1 + (size_t)i * FFH * HDIM, HDIM, 7, 8};
    for (int i = 0; i < 3; i++)
        ds.d[di++] = {fw2 + (size_t)i * FFH * HDIM, wt_f2 + (size_t)i * HDIM * FFH, FFH, 8, 7};
    wconv_kernel<<<dim3(32, 15), 256, 0, stream>>>(ds);

    // ---- CSR build ----
    (void)hipMemsetAsync(deg, 0, (size_t)n * 4, stream);
    (void)hipMemsetAsync(asum, 0, (size_t)2 * n * 4, stream);
    deg_kernel<<<(E + 255) / 256, 256, 0, stream>>>(ei, eattr, deg, asum, E);
    scan_kernel<<<1, 1024, 0, stream>>>(deg, row_ptr, cur, n);
    scatter_kernel<<<(EP + 255) / 256, 256, 0, stream>>>(ei, eattr, deg, asum, cur, csr, E, n);

    // ---- Embedding: H0(+H0h) = xh @ wt_emb + emb_b (B-stationary) ----
    gemm_bstat<64, 2><<<dim3(1, numMT), 256, 0, stream>>>(
        xh, 64, wt_emb, emb_b, H0, H0h, n, HDIM, numMT);

    // ---- 3 GATv2 + FFN layers ----
    for (int i = 0; i < 3; i++) {
        int concat = (i < 2);
        // fused lin_l|lin_r: XLR[n][1024] (B-stationary, barrier-free M loop)
        gemm_bstat<128, 1><<<dim3(8, 80), 256, 0, stream>>>(
            H0h, HDIM, wt_llr + (size_t)i * 1024 * HDIM, nullptr,
            nullptr, XLR, n, 1024, numMT);
        // gat: concat -> f16 into XR half; non-concat -> fused mean+bias+res+LN
        gat_edge_kernel<<<(n + 3) / 4, 256, 0, stream>>>(
            XLR, row_ptr, csr,
            lin_edge + (size_t)i * 2 * HH, attw + (size_t)i * HH,
            concat ? (cb01 + (size_t)i * HH) : cb2,
            XLR + 512, H1,
            H0, n1g + (size_t)i * HDIM, n1b + (size_t)i * HDIM, H1h,
            n, concat);
        if (concat) {
            // H1,H1h = LN(proj(gatout) + pb + H0)
            gemm_ln<<<(n + 63) / 64, 256, 0, stream>>>(
                XLR + 512, 1024, wt_proj + (size_t)i * HDIM * HH,
                proj_b + (size_t)i * HDIM, H0,
                n1g + (size_t)i * HDIM, n1b + (size_t)i * HDIM,
                H1, H1h, n, HH);
        }
        // {out|H0,H0h} = LN(GELU(H1h@W1+b1)@W2 + b2 + H1)
        float* lnout = (i == 2) ? out : H0;
        _Float16* lnout16 = (i == 2) ? nullptr : H0h;
        ffn_fused<<<(n + 63) / 64, 256, 0, stream>>>(
            H1h, wt_f1 + (size_t)i * FFH * HDIM, fb1 + (size_t)i * FFH,
            wt_f2 + (size_t)i * HDIM * FFH, fb2 + (size_t)i * HDIM, H1,
            n2g + (size_t)i * HDIM, n2b + (size_t)i * HDIM,
            lnout, lnout16, n);
    }
}

// Round 10
// 564.875 us; speedup vs baseline: 1.2814x; 1.0067x over previous
//
#include <hip/hip_runtime.h>
#include <math.h>

#define IN_DIM 16
#define HDIM   128
#define HEADS  4
#define HH     512   // HEADS*HDIM
#define FFH    256   // 2*HDIM
#define NEG_SLOPE 0.2f

typedef _Float16 half8 __attribute__((ext_vector_type(8)));
typedef _Float16 h8 __attribute__((ext_vector_type(8)));
typedef _Float16 h4 __attribute__((ext_vector_type(4)));
typedef _Float16 h2 __attribute__((ext_vector_type(2)));
typedef float f32x4 __attribute__((ext_vector_type(4)));

struct __align__(8) Edge { int src; _Float16 ea0, ea1; };

static __device__ inline float hsum8(h8 v) {
    h4 a = __builtin_shufflevector(v, v, 0, 1, 2, 3) +
           __builtin_shufflevector(v, v, 4, 5, 6, 7);
    h2 b = __builtin_shufflevector(a, a, 0, 1) +
           __builtin_shufflevector(a, a, 2, 3);
    return (float)b[0] + (float)b[1];
}

// ---------------------------------------------------------------------------
// x pad: xh[n][64] = f16(x[n][16]) zero-padded
// ---------------------------------------------------------------------------
__global__ void xpad_kernel(const float* __restrict__ x, _Float16* __restrict__ xh, int n) {
    int idx = blockIdx.x * 256 + threadIdx.x;
    if (idx >= n * 64) return;
    int r = idx >> 6, k = idx & 63;
    xh[idx] = (k < IN_DIM) ? (_Float16)x[r * IN_DIM + k] : (_Float16)0.0f;
}

// ---------------------------------------------------------------------------
// Weight convert+transpose+K-pad: W[Ksrc][N] fp32 -> WT[N][Kd] f16 (zero pad)
// ---------------------------------------------------------------------------
struct WDesc { const float* src; _Float16* dst; int Ksrc; int lgKd; int lgN; };
struct WDescs { WDesc d[15]; };
__global__ void wconv_kernel(WDescs ds) {
    WDesc w = ds.d[blockIdx.y];
    int Kd = 1 << w.lgKd;
    int total = 1 << (w.lgKd + w.lgN);
    for (int idx = blockIdx.x * 256 + threadIdx.x; idx < total; idx += gridDim.x * 256) {
        int n2 = idx >> w.lgKd, k = idx & (Kd - 1);
        w.dst[idx] = (k < w.Ksrc) ? (_Float16)w.src[(k << w.lgN) + n2] : (_Float16)0.0f;
    }
}

// ---------------------------------------------------------------------------
// Preprocess: degree + edge_attr sums (self-loop fill_value='mean')
// ---------------------------------------------------------------------------
__global__ void deg_kernel(const int* __restrict__ ei, const float* __restrict__ eattr,
                           float* deg, float* asum, int E) {
    int e = blockIdx.x * blockDim.x + threadIdx.x;
    if (e >= E) return;
    int d = ei[E + e];
    atomicAdd(&deg[d], 1.0f);
    atomicAdd(&asum[2 * d], eattr[2 * e]);
    atomicAdd(&asum[2 * d + 1], eattr[2 * e + 1]);
}

__global__ void scan_kernel(const float* __restrict__ deg, int* row_ptr, int* cur, int n) {
    __shared__ int sums[1024];
    int tid = threadIdx.x;
    int per = (n + 1023) / 1024;
    int s0 = tid * per;
    int s1 = s0 + per; if (s1 > n) s1 = n;
    int s = 0;
    for (int i = s0; i < s1; i++) s += (int)deg[i] + 1;
    int mysum = s;
    sums[tid] = s;
    __syncthreads();
    for (int dd = 1; dd < 1024; dd <<= 1) {
        int t = (tid >= dd) ? sums[tid - dd] : 0;
        __syncthreads();
        sums[tid] += t;
        __syncthreads();
    }
    int run = sums[tid] - mysum;   // exclusive prefix
    for (int i = s0; i < s1; i++) {
        row_ptr[i] = run; cur[i] = run;
        run += (int)deg[i] + 1;
    }
    if (tid == 1023) row_ptr[n] = sums[1023];
}

__global__ void scatter_kernel(const int* __restrict__ ei, const float* __restrict__ eattr,
                               const float* __restrict__ deg, const float* __restrict__ asum,
                               int* cur, Edge* csr, int E, int n) {
    int i = blockIdx.x * blockDim.x + threadIdx.x;
    if (i >= E + n) return;
    Edge ed;
    int pos;
    if (i < E) {
        int d = ei[E + i];
        pos = atomicAdd(&cur[d], 1);
        ed.src = ei[i];
        ed.ea0 = (_Float16)eattr[2 * i];
        ed.ea1 = (_Float16)eattr[2 * i + 1];
    } else {
        int nd = i - E;
        float dv = fmaxf(deg[nd], 1.0f);
        pos = atomicAdd(&cur[nd], 1);
        ed.src = nd;
        ed.ea0 = (_Float16)(asum[2 * nd] / dv);
        ed.ea1 = (_Float16)(asum[2 * nd + 1] / dv);
    }
    csr[pos] = ed;
}

// ---------------------------------------------------------------------------
// B-stationary MFMA GEMM for K<=128 (see r9 notes): BT staged once, B-frags
// in registers, barrier-free grid-stride M loop, A direct from global.
// ---------------------------------------------------------------------------
template <int KT, int OUTMODE>
__global__ __launch_bounds__(256) void gemm_bstat(const _Float16* __restrict__ A, int lda,
                                                  const _Float16* __restrict__ BT,
                                                  const float* __restrict__ bias,
                                                  float* __restrict__ C32,
                                                  _Float16* __restrict__ C16,
                                                  int M, int Nstride, int numMT) {
    const int PAD = 8, KC = KT / 32;
    __shared__ _Float16 Bs[128][KT + PAD];
    int tid = threadIdx.x;
    int wave = tid >> 6, lane = tid & 63;
    int quad = lane >> 4, l16 = lane & 15;
    int wrow = (wave >> 1) * 32, wcol = (wave & 1) * 64;
    int n0 = blockIdx.x * 128;

#pragma unroll
    for (int t = 0; t < KT / 16; t++) {
        int idx = tid + t * 256;
        int r = idx / (KT / 8), kb = (idx % (KT / 8)) * 8;
        *(half8*)&Bs[r][kb] = *(const half8*)(BT + (size_t)(n0 + r) * KT + kb);
    }
    __syncthreads();

    half8 bfrag[4][KC];
#pragma unroll
    for (int j = 0; j < 4; j++)
#pragma unroll
        for (int kc = 0; kc < KC; kc++)
            bfrag[j][kc] = *(const half8*)&Bs[wcol + j * 16 + l16][kc * 32 + quad * 8];

    float biasj[4];
#pragma unroll
    for (int j = 0; j < 4; j++)
        biasj[j] = bias ? bias[n0 + wcol + j * 16 + l16] : 0.0f;

    for (int mt = blockIdx.y; mt < numMT; mt += gridDim.y) {
        int rbase = mt * 64 + wrow;
        half8 af[2][KC];
#pragma unroll
        for (int i = 0; i < 2; i++) {
            int row = rbase + i * 16 + l16;
#pragma unroll
            for (int kc = 0; kc < KC; kc++)
                af[i][kc] = (row < M) ? *(const half8*)(A + (size_t)row * lda + kc * 32 + quad * 8)
                                      : (half8)(_Float16)0.0f;
        }
        f32x4 acc[2][4] = {};
#pragma unroll
        for (int kc = 0; kc < KC; kc++)
#pragma unroll
            for (int i = 0; i < 2; i++)
#pragma unroll
                for (int j = 0; j < 4; j++)
                    acc[i][j] = __builtin_amdgcn_mfma_f32_16x16x32_f16(af[i][kc], bfrag[j][kc], acc[i][j], 0, 0, 0);
#pragma unroll
        for (int i = 0; i < 2; i++) {
#pragma unroll
            for (int r = 0; r < 4; r++) {
                int row = rbase + i * 16 + quad * 4 + r;
                if (row >= M) continue;
#pragma unroll
                for (int j = 0; j < 4; j++) {
                    int col = n0 + wcol + j * 16 + l16;
                    float v = acc[i][j][r] + biasj[j];
                    if (OUTMODE == 2)
                        C32[(size_t)row * Nstride + col] = v;
                    C16[(size_t)row * Nstride + col] = (_Float16)v;
                }
            }
        }
    }
}

// ---------------------------------------------------------------------------
// Fused GEMM(+bias) + residual + LayerNorm for N=128, register-resident LN.
// ---------------------------------------------------------------------------
__global__ __launch_bounds__(256) void gemm_ln(const _Float16* __restrict__ A, int lda,
                                               const _Float16* __restrict__ BT,
                                               const float* __restrict__ bias,
                                               const float* __restrict__ R,
                                               const float* __restrict__ g,
                                               const float* __restrict__ b,
                                               float* __restrict__ C32,
                                               _Float16* __restrict__ C16,
                                               int M, int K) {
    const int BK = 64, PAD = 8;
    __shared__ _Float16 As[64][BK + PAD];
    __shared__ _Float16 Bs[128][BK + PAD];
    int tid = threadIdx.x;
    int wave = tid >> 6, lane = tid & 63;
    int quad = lane >> 4, l16 = lane & 15;
    int mBase = blockIdx.x * 64;

    f32x4 acc[8] = {};

    for (int k0 = 0; k0 < K; k0 += BK) {
#pragma unroll
        for (int t = 0; t < 2; t++) {
            int idx = tid + t * 256;
            int r = idx >> 3, kb = (idx & 7) * 8;
            half8 hv = {};
            int grow = mBase + r;
            if (grow < M) hv = *(const half8*)(A + (size_t)grow * lda + k0 + kb);
            *(half8*)&As[r][kb] = hv;
        }
#pragma unroll
        for (int t = 0; t < 4; t++) {
            int idx = tid + t * 256;
            int r = idx >> 3, kb = (idx & 7) * 8;
            *(half8*)&Bs[r][kb] = *(const half8*)(BT + (size_t)r * K + k0 + kb);
        }
        __syncthreads();
#pragma unroll
        for (int kc = 0; kc < 2; kc++) {
            half8 a = *(const half8*)&As[wave * 16 + l16][kc * 32 + quad * 8];
#pragma unroll
            for (int j = 0; j < 8; j++) {
                half8 bb = *(const half8*)&Bs[j * 16 + l16][kc * 32 + quad * 8];
                acc[j] = __builtin_amdgcn_mfma_f32_16x16x32_f16(a, bb, acc[j], 0, 0, 0);
            }
        }
        __syncthreads();
    }

    float gj[8], bj[8], biasj[8];
#pragma unroll
    for (int j = 0; j < 8; j++) {
        int col = j * 16 + l16;
        biasj[j] = bias[col];
        gj[j] = g[col];
        bj[j] = b[col];
    }
    int row0 = mBase + wave * 16 + quad * 4;
    float sum[4] = {}, sq[4] = {};
#pragma unroll
    for (int r = 0; r < 4; r++) {
        int row = row0 + r;
        bool ok = row < M;
        size_t base = (size_t)row * HDIM;
#pragma unroll
        for (int j = 0; j < 8; j++) {
            float v = acc[j][r] + biasj[j] + (ok ? R[base + j * 16 + l16] : 0.0f);
            acc[j][r] = v;
            sum[r] += v;
            sq[r] += v * v;
        }
    }
#pragma unroll
    for (int r = 0; r < 4; r++) {
#pragma unroll
        for (int off = 1; off < 16; off <<= 1) {
            sum[r] += __shfl_xor(sum[r], off);
            sq[r] += __shfl_xor(sq[r], off);
        }
    }
#pragma unroll
    for (int r = 0; r < 4; r++) {
        int row = row0 + r;
        if (row >= M) continue;
        size_t base = (size_t)row * HDIM;
        float mu = sum[r] * (1.0f / HDIM);
        float var = sq[r] * (1.0f / HDIM) - mu * mu;
        float invstd = rsqrtf(var + 1e-5f);
#pragma unroll
        for (int j = 0; j < 8; j++) {
            float o = (acc[j][r] - mu) * invstd * gj[j] + bj[j];
            C32[base + j * 16 + l16] = o;
            if (C16) C16[base + j * 16 + l16] = (_Float16)o;
        }
    }
}

// ---------------------------------------------------------------------------
// Fused FFN: C = LN(GELU(A@W1T + b1)@W2T + b2 + R) * g + b.
// ---------------------------------------------------------------------------
__global__ __launch_bounds__(256) void ffn_fused(const _Float16* __restrict__ A,
                                                 const _Float16* __restrict__ W1T,
                                                 const float* __restrict__ b1,
                                                 const _Float16* __restrict__ W2T,
                                                 const float* __restrict__ b2,
                                                 const float* __restrict__ R,
                                                 const float* __restrict__ g,
                                                 const float* __restrict__ b,
                                                 float* __restrict__ C32,
                                                 _Float16* __restrict__ C16,
                                                 int M) {
    __shared__ _Float16 Ws[128][128 + 8];
    __shared__ _Float16 Mid[64][256 + 8];
    int tid = threadIdx.x;
    int wave = tid >> 6, lane = tid & 63;
    int quad = lane >> 4, l16 = lane & 15;
    int mBase = blockIdx.x * 64;

    half8 afrag[4];
    {
        int row = mBase + wave * 16 + l16;
#pragma unroll
        for (int kc = 0; kc < 4; kc++) {
            if (row < M)
                afrag[kc] = *(const half8*)(A + (size_t)row * HDIM + kc * 32 + quad * 8);
            else
                afrag[kc] = (half8)(_Float16)0.0f;
        }
    }

#pragma unroll
    for (int h = 0; h < 2; h++) {
        if (h) __syncthreads();
#pragma unroll
        for (int t = 0; t < 8; t++) {
            int idx = tid + t * 256;
            int r = idx >> 4, kb = (idx & 15) * 8;
            *(half8*)&Ws[r][kb] = *(const half8*)(W1T + (size_t)(h * 128 + r) * HDIM + kb);
        }
        __syncthreads();
        f32x4 acc[8] = {};
#pragma unroll
        for (int kc = 0; kc < 4; kc++) {
#pragma unroll
            for (int j = 0; j < 8; j++) {
                half8 bb = *(const half8*)&Ws[j * 16 + l16][kc * 32 + quad * 8];
                acc[j] = __builtin_amdgcn_mfma_f32_16x16x32_f16(afrag[kc], bb, acc[j], 0, 0, 0);
            }
        }
#pragma unroll
        for (int j = 0; j < 8; j++) {
            float bj1 = b1[h * 128 + j * 16 + l16];
#pragma unroll
            for (int r = 0; r < 4; r++) {
                float v = acc[j][r] + bj1;
                v = 0.5f * v * (1.0f + erff(v * 0.70710678118654752f));
                Mid[wave * 16 + quad * 4 + r][h * 128 + j * 16 + l16] = (_Float16)v;
            }
        }
    }
    __syncthreads();

    f32x4 acc2[8] = {};
#pragma unroll
    for (int kc2 = 0; kc2 < 2; kc2++) {
        if (kc2) __syncthreads();
#pragma unroll
        for (int t = 0; t < 8; t++) {
            int idx = tid + t * 256;
            int r = idx >> 4, kb = (idx & 15) * 8;
            *(half8*)&Ws[r][kb] = *(const half8*)(W2T + (size_t)r * FFH + kc2 * 128 + kb);
        }
        __syncthreads();
#pragma unroll
        for (int kc = 0; kc < 4; kc++) {
            half8 am = *(const half8*)&Mid[wave * 16 + l16][kc2 * 128 + kc * 32 + quad * 8];
#pragma unroll
            for (int j = 0; j < 8; j++) {
                half8 bb = *(const half8*)&Ws[j * 16 + l16][kc * 32 + quad * 8];
                acc2[j] = __builtin_amdgcn_mfma_f32_16x16x32_f16(am, bb, acc2[j], 0, 0, 0);
            }
        }
    }

    float gj[8], bj[8], b2j[8];
#pragma unroll
    for (int j = 0; j < 8; j++) {
        int col = j * 16 + l16;
        b2j[j] = b2[col];
        gj[j] = g[col];
        bj[j] = b[col];
    }
    int row0 = mBase + wave * 16 + quad * 4;
    float sum[4] = {}, sq[4] = {};
#pragma unroll
    for (int r = 0; r < 4; r++) {
        int row = row0 + r;
        bool ok = row < M;
        size_t base = (size_t)row * HDIM;
#pragma unroll
        for (int j = 0; j < 8; j++) {
            float v = acc2[j][r] + b2j[j] + (ok ? R[base + j * 16 + l16] : 0.0f);
            acc2[j][r] = v;
            sum[r] += v;
            sq[r] += v * v;
        }
    }
#pragma unroll
    for (int r = 0; r < 4; r++) {
#pragma unroll
        for (int off = 1; off < 16; off <<= 1) {
            sum[r] += __shfl_xor(sum[r], off);
            sq[r] += __shfl_xor(sq[r], off);
        }
    }
#pragma unroll
    for (int r = 0; r < 4; r++) {
        int row = row0 + r;
        if (row >= M) continue;
        size_t base = (size_t)row * HDIM;
        float mu = sum[r] * (1.0f / HDIM);
        float var = sq[r] * (1.0f / HDIM) - mu * mu;
        float invstd = rsqrtf(var + 1e-5f);
#pragma unroll
        for (int j = 0; j < 8; j++) {
            float o = (acc2[j][r] - mu) * invstd * gj[j] + bj[j];
            C32[base + j * 16 + l16] = o;
            if (C16) C16[base + j * 16 + l16] = (_Float16)o;
        }
    }
}

// ---------------------------------------------------------------------------
// GATv2 attention + aggregation, split-edge: 2 waves per dst node, each runs
// the 2-edge-unrolled online softmax on half the edge list; halves merged in
// LDS (flash-merge: rescale by exp(m - m*)). Epilogue by even wave.
// Block = 256 threads = 2 nodes x 2 waves.
// ---------------------------------------------------------------------------
__global__ __launch_bounds__(256) void gat_edge_kernel(
    const _Float16* __restrict__ XLR,
    const int* __restrict__ row_ptr, const Edge* __restrict__ csr,
    const float* __restrict__ We,    // [2,512]
    const float* __restrict__ attW,  // [512]
    const float* __restrict__ cbias, // [512] or [128]
    _Float16* __restrict__ OUT16, float* __restrict__ OUT32,
    const float* __restrict__ R, const float* __restrict__ lng,
    const float* __restrict__ lnb, _Float16* __restrict__ OUT16h,
    int n, int concat) {
    __shared__ float sM[2][64], sL[2][64];
    __shared__ h8 sAcc[2][64];
    int tid = threadIdx.x;
    int wave = tid >> 6, lane = tid & 63;
    int nodeIdx = wave >> 1;       // 0..1
    int half = wave & 1;
    int node = blockIdx.x * 2 + nodeIdx;
    bool active = node < n;
    int c0 = lane * 8;

    h8 xr8 = (h8)(_Float16)0.0f;
    h8 w08, w18, att8;
#pragma unroll
    for (int k = 0; k < 8; k++) {
        w08[k] = (_Float16)We[c0 + k];
        w18[k] = (_Float16)We[HH + c0 + k];
        att8[k] = (_Float16)attW[c0 + k];
    }
    const _Float16 slope = (_Float16)NEG_SLOPE;

    h8 acc2 = (h8)(_Float16)0.0f;
    float m = -INFINITY, l = 0.0f;

    if (active) {
        xr8 = *(const h8*)(XLR + (size_t)node * 1024 + 512 + c0);
        int beg = row_ptr[node], end = row_ptr[node + 1];
        int mid = beg + ((end - beg + 1) >> 1);
        int b0 = half ? mid : beg;
        int e0 = half ? end : mid;
        int j = b0;
        for (; j + 1 < e0; j += 2) {
            Edge eg0 = csr[j], eg1 = csr[j + 1];
            h8 x0 = *(const h8*)(XLR + (size_t)eg0.src * 1024 + c0);
            h8 x1 = *(const h8*)(XLR + (size_t)eg1.src * 1024 + c0);
            h8 v0 = x0 + (xr8 + w08 * eg0.ea0 + w18 * eg0.ea1);
            h8 v1 = x1 + (xr8 + w08 * eg1.ea0 + w18 * eg1.ea1);
            v0 = __builtin_elementwise_max(v0, v0 * slope);
            v1 = __builtin_elementwise_max(v1, v1 * slope);
            float p0 = hsum8(v0 * att8);
            float p1 = hsum8(v1 * att8);
            p0 += __shfl_xor(p0, 1); p1 += __shfl_xor(p1, 1);
            p0 += __shfl_xor(p0, 2); p1 += __shfl_xor(p1, 2);
            p0 += __shfl_xor(p0, 4); p1 += __shfl_xor(p1, 4);
            p0 += __shfl_xor(p0, 8); p1 += __shfl_xor(p1, 8);
            float mnew = fmaxf(m, fmaxf(p0, p1));
            float sc = __expf(m - mnew);
            float e0f = __expf(p0 - mnew);
            float e1f = __expf(p1 - mnew);
            l = l * sc + e0f + e1f;
            acc2 = acc2 * (_Float16)sc + x0 * (_Float16)e0f + x1 * (_Float16)e1f;
            m = mnew;
        }
        if (j < e0) {
            Edge eg0 = csr[j];
            h8 x0 = *(const h8*)(XLR + (size_t)eg0.src * 1024 + c0);
            h8 v0 = x0 + (xr8 + w08 * eg0.ea0 + w18 * eg0.ea1);
            v0 = __builtin_elementwise_max(v0, v0 * slope);
            float p0 = hsum8(v0 * att8);
            p0 += __shfl_xor(p0, 1);
            p0 += __shfl_xor(p0, 2);
            p0 += __shfl_xor(p0, 4);
            p0 += __shfl_xor(p0, 8);
            float mnew = fmaxf(m, p0);
            float sc = __expf(m - mnew);
            float e0f = __expf(p0 - mnew);
            l = l * sc + e0f;
            acc2 = acc2 * (_Float16)sc + x0 * (_Float16)e0f;
            m = mnew;
        }
    }

    // ---- merge the two halves via LDS ----
    if (half == 1) {
        sM[nodeIdx][lane] = m;
        sL[nodeIdx][lane] = l;
        sAcc[nodeIdx][lane] = acc2;
    }
    __syncthreads();
    if (half != 0 || !active) return;
    {
        float mB = sM[nodeIdx][lane];
        float lB = sL[nodeIdx][lane];
        h8 accB = sAcc[nodeIdx][lane];
        float mS = fmaxf(m, mB);
        float sA = __expf(m - mS);          // m is finite (half0 has >=1 edge)
        float sB = __expf(mB - mS);         // exp(-inf)=0 handles empty half
        l = l * sA + lB * sB;
        acc2 = acc2 * (_Float16)sA + accB * (_Float16)sB;
    }

    float invf = 1.0f / (l + 1e-16f);
    if (concat) {
        h8 o = acc2 * (_Float16)invf;
#pragma unroll
        for (int k = 0; k < 8; k++) o[k] = o[k] + (_Float16)cbias[c0 + k];
        *(h8*)(OUT16 + (size_t)node * 1024 + c0) = o;
    } else {
        float o8[8];
#pragma unroll
        for (int k = 0; k < 8; k++) {
            float a = (float)acc2[k] * invf;
            a += __shfl_xor(a, 16);
            a += __shfl_xor(a, 32);
            o8[k] = a;
        }
        float v8[8];
        float sum = 0.0f, sq = 0.0f;
        if (lane < 16) {
#pragma unroll
            for (int k = 0; k < 8; k++) {
                float v = o8[k] * 0.25f + cbias[c0 + k] + R[(size_t)node * HDIM + c0 + k];
                v8[k] = v;
                sum += v;
                sq += v * v;
            }
        }
#pragma unroll
        for (int off = 1; off < 16; off <<= 1) {
            sum += __shfl_xor(sum, off);
            sq += __shfl_xor(sq, off);
        }
        if (lane < 16) {
            float mu = sum * (1.0f / HDIM);
            float var = sq * (1.0f / HDIM) - mu * mu;
            float invstd = rsqrtf(var + 1e-5f);
#pragma unroll
            for (int k = 0; k < 8; k++) {
                float o = (v8[k] - mu) * invstd * lng[c0 + k] + lnb[c0 + k];
                OUT32[(size_t)node * HDIM + c0 + k] = o;
                OUT16h[(size_t)node * HDIM + c0 + k] = (_Float16)o;
            }
        }
    }
}

// ---------------------------------------------------------------------------
extern "C" void kernel_launch(void* const* d_in, const int* in_sizes, int n_in,
                              void* d_out, int out_size, void* d_ws, size_t ws_size,
                              hipStream_t stream) {
    const float* x        = (const float*)d_in[0];
    const int*   ei       = (const int*)d_in[1];
    const float* eattr    = (const float*)d_in[2];
    const float* emb_w    = (const float*)d_in[3];
    const float* emb_b    = (const float*)d_in[4];
    const float* lin_l    = (const float*)d_in[5];
    const float* lin_r    = (const float*)d_in[6];
    const float* lin_edge = (const float*)d_in[7];
    const float* attw     = (const float*)d_in[8];
    const float* cb01     = (const float*)d_in[9];
    const float* cb2      = (const float*)d_in[10];
    const float* proj_w   = (const float*)d_in[11];
    const float* proj_b   = (const float*)d_in[12];
    const float* n1g      = (const float*)d_in[13];
    const float* n1b      = (const float*)d_in[14];
    const float* n2g      = (const float*)d_in[15];
    const float* n2b      = (const float*)d_in[16];
    const float* fw1      = (const float*)d_in[17];
    const float* fb1      = (const float*)d_in[18];
    const float* fw2      = (const float*)d_in[19];
    const float* fb2      = (const float*)d_in[20];
    float* out = (float*)d_out;

    const int n = in_sizes[0] / IN_DIM;   // 20000
    const int E = in_sizes[2] / 2;        // 320000
    const int EP = E + n;
    const int numMT = (n + 63) / 64;

    size_t off = 0;
    auto alloc = [&](size_t bytes) {
        void* p = (char*)d_ws + off;
        off += (bytes + 255) & ~(size_t)255;
        return p;
    };
    float* deg     = (float*)alloc((size_t)n * 4);
    float* asum    = (float*)alloc((size_t)2 * n * 4);
    int*   row_ptr = (int*)alloc((size_t)(n + 1) * 4);
    int*   cur     = (int*)alloc((size_t)n * 4);
    Edge*  csr     = (Edge*)alloc((size_t)EP * 8);
    float* H0      = (float*)alloc((size_t)n * HDIM * 4);
    float* H1      = (float*)alloc((size_t)n * HDIM * 4);
    _Float16* H0h  = (_Float16*)alloc((size_t)n * HDIM * 2);
    _Float16* H1h  = (_Float16*)alloc((size_t)n * HDIM * 2);
    _Float16* XLR  = (_Float16*)alloc((size_t)n * 1024 * 2);
    _Float16* xh   = (_Float16*)alloc((size_t)n * 64 * 2);
    _Float16* wt_emb  = (_Float16*)alloc((size_t)HDIM * 64 * 2);
    _Float16* wt_llr  = (_Float16*)alloc((size_t)3 * 1024 * HDIM * 2);
    _Float16* wt_proj = (_Float16*)alloc((size_t)2 * HDIM * HH * 2);
    _Float16* wt_f1   = (_Float16*)alloc((size_t)3 * FFH * HDIM * 2);
    _Float16* wt_f2   = (_Float16*)alloc((size_t)3 * HDIM * FFH * 2);
    (void)ws_size;

    // ---- input prep ----
    xpad_kernel<<<(n * 64 + 255) / 256, 256, 0, stream>>>(x, xh, n);
    WDescs ds;
    int di = 0;
    ds.d[di++] = {emb_w, wt_emb, IN_DIM, 6, 7};
    for (int i = 0; i < 3; i++) {
        ds.d[di++] = {lin_l + (size_t)i * HDIM * HH, wt_llr + (size_t)i * 1024 * HDIM, HDIM, 7, 9};
        ds.d[di++] = {lin_r + (size_t)i * HDIM * HH, wt_llr + (size_t)i * 1024 * HDIM + (size_t)512 * HDIM, HDIM, 7, 9};
    }
    for (int i = 0; i < 2; i++)
        ds.d[di++] = {proj_w + (size_t)i * HH * HDIM, wt_proj + (size_t)i * HDIM * HH, HH, 9, 7};
    for (int i = 0; i < 3; i++)
        ds.d[di++] = {fw1 + (size_t)i * HDIM * FFH, wt_f1 + (size_t)i * FFH * HDIM, HDIM, 7, 8};
    for (int i = 0; i < 3; i++)
        ds.d[di++] = {fw2 + (size_t)i * FFH * HDIM, wt_f2 + (size_t)i * HDIM * FFH, FFH, 8, 7};
    wconv_kernel<<<dim3(32, 15), 256, 0, stream>>>(ds);

    // ---- CSR build ----
    (void)hipMemsetAsync(deg, 0, (size_t)n * 4, stream);
    (void)hipMemsetAsync(asum, 0, (size_t)2 * n * 4, stream);
    deg_kernel<<<(E + 255) / 256, 256, 0, stream>>>(ei, eattr, deg, asum, E);
    scan_kernel<<<1, 1024, 0, stream>>>(deg, row_ptr, cur, n);
    scatter_kernel<<<(EP + 255) / 256, 256, 0, stream>>>(ei, eattr, deg, asum, cur, csr, E, n);

    // ---- Embedding: H0(+H0h) = xh @ wt_emb + emb_b (B-stationary) ----
    gemm_bstat<64, 2><<<dim3(1, numMT), 256, 0, stream>>>(
        xh, 64, wt_emb, emb_b, H0, H0h, n, HDIM, numMT);

    // ---- 3 GATv2 + FFN layers ----
    for (int i = 0; i < 3; i++) {
        int concat = (i < 2);
        // fused lin_l|lin_r: XLR[n][1024] (B-stationary, barrier-free M loop)
        gemm_bstat<128, 1><<<dim3(8, 80), 256, 0, stream>>>(
            H0h, HDIM, wt_llr + (size_t)i * 1024 * HDIM, nullptr,
            nullptr, XLR, n, 1024, numMT);
        // gat: 2 waves/node split-edge; concat -> f16 into XR half;
        // non-concat -> fused mean+bias+res+LN
        gat_edge_kernel<<<(n + 1) / 2, 256, 0, stream>>>(
            XLR, row_ptr, csr,
            lin_edge + (size_t)i * 2 * HH, attw + (size_t)i * HH,
            concat ? (cb01 + (size_t)i * HH) : cb2,
            XLR + 512, H1,
            H0, n1g + (size_t)i * HDIM, n1b + (size_t)i * HDIM, H1h,
            n, concat);
        if (concat) {
            // H1,H1h = LN(proj(gatout) + pb + H0)
            gemm_ln<<<(n + 63) / 64, 256, 0, stream>>>(
                XLR + 512, 1024, wt_proj + (size_t)i * HDIM * HH,
                proj_b + (size_t)i * HDIM, H0,
                n1g + (size_t)i * HDIM, n1b + (size_t)i * HDIM,
                H1, H1h, n, HH);
        }
        // {out|H0,H0h} = LN(GELU(H1h@W1+b1)@W2 + b2 + H1)
        float* lnout = (i == 2) ? out : H0;
        _Float16* lnout16 = (i == 2) ? nullptr : H0h;
        ffn_fused<<<(n + 63) / 64, 256, 0, stream>>>(
            H1h, wt_f1 + (size_t)i * FFH * HDIM, fb1 + (size_t)i * FFH,
            wt_f2 + (size_t)i * HDIM * FFH, fb2 + (size_t)i * HDIM, H1,
            n2g + (size_t)i * HDIM, n2b + (size_t)i * HDIM,
            lnout, lnout16, n);
    }
}